// Round 1
// baseline (1003.484 us; speedup 1.0000x reference)
//
#include <hip/hip_runtime.h>
#include <cstdint>
#include <cstddef>

#define NR_EMB 4096
#define DD 128
#define NTOT 65536   // 32*2048

// ---------------- workspace layout (bytes) ----------------
#define WS_DWT   0u                       // float[4096*128]  (K-major: dwT[k*128+d])
#define WS_CNT   2097152u                 // uint[4096]
#define WS_SCAL  (WS_CNT + 16384u)        // float[16] : [0]=n_total
#define WS_COLN  (WS_SCAL + 64u)          // float[4096]
#define WS_IDX   (WS_COLN + 16384u)       // int[65536]
#define WS_EMBT  (WS_IDX + 262144u)       // float[4096*128] (embT[k*128+d])
#define WS_LPART (WS_EMBT + 2097152u)     // float[8192] per-block loss partials
// total = WS_LPART + 32768 = 4,522,048 bytes

// ---------------- output layout (floats) ----------------
#define OUT_Q      0u          // 8388608
#define OUT_LOSS   8388608u
#define OUT_PERP   8388609u
#define OUT_EMB    8388610u    // 524288  [D,K]
#define OUT_CLUS   8912898u    // 4096
#define OUT_DW     8916994u    // 524288  [D,K]

__global__ __launch_bounds__(256) void k_colnorm(const float* __restrict__ E,
                                                 float* __restrict__ coln) {
    int k = blockIdx.x * 256 + threadIdx.x;
    float acc = 0.f;
    for (int d = 0; d < DD; ++d) {
        float v = E[(size_t)d * NR_EMB + k];
        acc = fmaf(v, v, acc);
    }
    coln[k] = acc;
}

// 64 samples per block; K in tiles of 64; 16x16 threads, 4x4 micro-tile.
__global__ __launch_bounds__(256) void k_dist(const float* __restrict__ x,
                                              const float* __restrict__ E,
                                              const float* __restrict__ coln,
                                              int* __restrict__ idx_out,
                                              unsigned int* __restrict__ counts,
                                              float* __restrict__ dwT) {
    __shared__ float xs[64][132];   // sample-major, padded (132 floats keeps 16B align)
    __shared__ float Et[128][64];   // d-major, 64 codes contiguous
    __shared__ float xn[64];
    __shared__ int   fidx[64];

    const int tid = threadIdx.x;
    const int n0  = blockIdx.x * 64;

    // ---- stage x tile (fully coalesced: wave covers 2 contiguous rows) ----
    {
        int c  = tid & 31;   // float4 chunk within row
        int s0 = tid >> 5;   // 0..7
        #pragma unroll
        for (int p = 0; p < 8; ++p) {
            int s = s0 + p * 8;
            float4 v = *reinterpret_cast<const float4*>(&x[((size_t)(n0 + s)) * DD + c * 4]);
            *reinterpret_cast<float4*>(&xs[s][c * 4]) = v;
        }
    }
    __syncthreads();

    // ---- per-sample ||x||^2 ----
    if (tid < 64) {
        float acc = 0.f;
        for (int d = 0; d < DD; ++d) {
            float v = xs[tid][d];
            acc = fmaf(v, v, acc);
        }
        xn[tid] = acc;
    }
    __syncthreads();

    const int tx = tid & 15;   // code group
    const int ty = tid >> 4;   // sample group
    float xnr[4];
    float best[4];
    int   bidx[4];
    #pragma unroll
    for (int i = 0; i < 4; ++i) {
        xnr[i]  = xn[ty * 4 + i];
        best[i] = 3.4e38f;
        bidx[i] = 0;
    }

    for (int k0 = 0; k0 < NR_EMB; k0 += 64) {
        __syncthreads();   // previous tile's reads complete
        {   // stage E tile: rows d, 64 contiguous codes
            int cc = tid & 15;   // float4 chunk
            int rr = tid >> 4;   // 0..15
            #pragma unroll
            for (int p = 0; p < 8; ++p) {
                int d = rr + p * 16;
                float4 v = *reinterpret_cast<const float4*>(&E[(size_t)d * NR_EMB + k0 + cc * 4]);
                *reinterpret_cast<float4*>(&Et[d][cc * 4]) = v;
            }
        }
        __syncthreads();

        float acc[4][4];
        #pragma unroll
        for (int i = 0; i < 4; ++i)
            #pragma unroll
            for (int j = 0; j < 4; ++j) acc[i][j] = 0.f;

        #pragma unroll 4
        for (int d = 0; d < DD; ++d) {
            float a0 = xs[ty * 4 + 0][d];
            float a1 = xs[ty * 4 + 1][d];
            float a2 = xs[ty * 4 + 2][d];
            float a3 = xs[ty * 4 + 3][d];
            float4 b = *reinterpret_cast<const float4*>(&Et[d][tx * 4]);
            acc[0][0] = fmaf(a0, b.x, acc[0][0]);
            acc[0][1] = fmaf(a0, b.y, acc[0][1]);
            acc[0][2] = fmaf(a0, b.z, acc[0][2]);
            acc[0][3] = fmaf(a0, b.w, acc[0][3]);
            acc[1][0] = fmaf(a1, b.x, acc[1][0]);
            acc[1][1] = fmaf(a1, b.y, acc[1][1]);
            acc[1][2] = fmaf(a1, b.z, acc[1][2]);
            acc[1][3] = fmaf(a1, b.w, acc[1][3]);
            acc[2][0] = fmaf(a2, b.x, acc[2][0]);
            acc[2][1] = fmaf(a2, b.y, acc[2][1]);
            acc[2][2] = fmaf(a2, b.z, acc[2][2]);
            acc[2][3] = fmaf(a2, b.w, acc[2][3]);
            acc[3][0] = fmaf(a3, b.x, acc[3][0]);
            acc[3][1] = fmaf(a3, b.y, acc[3][1]);
            acc[3][2] = fmaf(a3, b.z, acc[3][2]);
            acc[3][3] = fmaf(a3, b.w, acc[3][3]);
        }

        float4 cn = *reinterpret_cast<const float4*>(&coln[k0 + tx * 4]);
        float cna[4] = {cn.x, cn.y, cn.z, cn.w};
        #pragma unroll
        for (int i = 0; i < 4; ++i) {
            #pragma unroll
            for (int j = 0; j < 4; ++j) {
                // numpy order: (||x||^2 - 2*dot) + ||e||^2
                float dist = (xnr[i] - 2.0f * acc[i][j]) + cna[j];
                int k = k0 + tx * 4 + j;
                if (dist < best[i]) { best[i] = dist; bidx[i] = k; }  // strict <: first idx wins
            }
        }
    }

    // ---- argmin reduce across the 16 threads sharing each sample (shfl, in-wave) ----
    #pragma unroll
    for (int i = 0; i < 4; ++i) {
        float bd = best[i];
        int   bi = bidx[i];
        #pragma unroll
        for (int m = 1; m < 16; m <<= 1) {
            float od = __shfl_xor(bd, m);
            int   oi = __shfl_xor(bi, m);
            if (od < bd || (od == bd && oi < bi)) { bd = od; bi = oi; }
        }
        if (tx == 0) {
            int s = ty * 4 + i;
            fidx[s] = bi;
            idx_out[n0 + s] = bi;
            atomicAdd(&counts[bi], 1u);
        }
    }
    __syncthreads();

    // ---- scatter x into dwT[k][d] (x tile still in LDS) ----
    {
        int d  = tid & 127;
        int s0 = tid >> 7;
        for (int s = s0; s < 64; s += 2) {
            int k = fidx[s];
            atomicAdd(&dwT[(size_t)k * DD + d], xs[s][d]);
        }
    }
}

__global__ __launch_bounds__(256) void k_stats(const float* __restrict__ emaC,
                                               const unsigned int* __restrict__ counts,
                                               float* __restrict__ outC,
                                               float* __restrict__ scal,
                                               float* __restrict__ outPerp) {
    __shared__ float rs[256], rp[256];
    int tid = threadIdx.x;
    float sc = 0.f, sp = 0.f;
    for (int k = tid; k < NR_EMB; k += 256) {
        float cnt = (float)counts[k];
        float nc  = emaC[k] * 0.99f + cnt * 0.01f;
        outC[k] = nc;
        sc += nc;
        float p = cnt * (1.0f / 65536.0f);
        sp += p * logf(p + 1e-10f);
    }
    rs[tid] = sc; rp[tid] = sp;
    __syncthreads();
    for (int off = 128; off > 0; off >>= 1) {
        if (tid < off) { rs[tid] += rs[tid + off]; rp[tid] += rp[tid + off]; }
        __syncthreads();
    }
    if (tid == 0) {
        scal[0] = rs[0];            // n_total
        outPerp[0] = expf(-rp[0]);  // perplexity
    }
}

__global__ __launch_bounds__(256) void k_emb(const float* __restrict__ emaDw,
                                             const float* __restrict__ emaC,
                                             const unsigned int* __restrict__ counts,
                                             const float* __restrict__ dwT,
                                             const float* __restrict__ scal,
                                             float* __restrict__ outDw,
                                             float* __restrict__ outEmb,
                                             float* __restrict__ embT) {
    int g = blockIdx.x * 256 + threadIdx.x;   // d-major over [D,K]
    int d = g >> 12;          // /4096
    int k = g & 4095;
    float dw  = emaDw[g] * 0.99f + dwT[k * DD + d] * 0.01f;
    float cnt = (float)counts[k];
    float nc  = emaC[k] * 0.99f + cnt * 0.01f;
    float n   = scal[0];
    float denom = n * (nc + 1e-5f) / (n + 0.04096f);   // K*1e-5 = 0.04096
    float e = dw / denom;
    outDw[g]  = dw;
    outEmb[g] = e;
    embT[k * DD + d] = e;
}

__global__ __launch_bounds__(256) void k_gather(const float* __restrict__ x,
                                                const float* __restrict__ embT,
                                                const int* __restrict__ idx,
                                                float* __restrict__ q,
                                                float* __restrict__ lpart) {
    __shared__ float wred[4];
    int g = blockIdx.x * 256 + threadIdx.x;   // float4 index, 0..2097151
    int n = g >> 5;
    int c = g & 31;
    int k = idx[n];
    float4 e  = *reinterpret_cast<const float4*>(&embT[(size_t)k * DD + c * 4]);
    float4 xv = *reinterpret_cast<const float4*>(&x[(size_t)n * DD + c * 4]);
    float dx = e.x - xv.x, dy = e.y - xv.y, dz = e.z - xv.z, dw = e.w - xv.w;
    // straight-through output replicated as x + (e - x) to mirror reference rounding
    float4 qo;
    qo.x = xv.x + dx; qo.y = xv.y + dy; qo.z = xv.z + dz; qo.w = xv.w + dw;
    *reinterpret_cast<float4*>(&q[(size_t)n * DD + c * 4]) = qo;
    float s = dx * dx + dy * dy + dz * dz + dw * dw;
    #pragma unroll
    for (int off = 32; off > 0; off >>= 1) s += __shfl_down(s, off);
    if ((threadIdx.x & 63) == 0) wred[threadIdx.x >> 6] = s;
    __syncthreads();
    if (threadIdx.x == 0)
        lpart[blockIdx.x] = wred[0] + wred[1] + wred[2] + wred[3];
}

__global__ __launch_bounds__(256) void k_final(const float* __restrict__ lpart,
                                               float* __restrict__ outLoss) {
    __shared__ float r[256];
    float s = 0.f;
    for (int i = threadIdx.x; i < 8192; i += 256) s += lpart[i];
    r[threadIdx.x] = s;
    __syncthreads();
    for (int off = 128; off > 0; off >>= 1) {
        if (threadIdx.x < off) r[threadIdx.x] += r[threadIdx.x + off];
        __syncthreads();
    }
    if (threadIdx.x == 0) outLoss[0] = r[0] * (1.0f / 8388608.0f);
}

extern "C" void kernel_launch(void* const* d_in, const int* in_sizes, int n_in,
                              void* d_out, int out_size, void* d_ws, size_t ws_size,
                              hipStream_t stream) {
    const float* x     = (const float*)d_in[0];   // [65536,128]
    const float* E     = (const float*)d_in[1];   // [128,4096]
    const float* emaC  = (const float*)d_in[2];   // [4096]
    const float* emaDw = (const float*)d_in[3];   // [128,4096]
    float* out = (float*)d_out;
    char*  ws  = (char*)d_ws;

    float*        dwT   = (float*)(ws + WS_DWT);
    unsigned int* cnts  = (unsigned int*)(ws + WS_CNT);
    float*        scal  = (float*)(ws + WS_SCAL);
    float*        coln  = (float*)(ws + WS_COLN);
    int*          idx   = (int*)(ws + WS_IDX);
    float*        embT  = (float*)(ws + WS_EMBT);
    float*        lpart = (float*)(ws + WS_LPART);

    // zero dwT + counts + scalars (one contiguous range)
    hipMemsetAsync(ws, 0, WS_SCAL + 64u, stream);

    k_colnorm<<<NR_EMB / 256, 256, 0, stream>>>(E, coln);
    k_dist<<<NTOT / 64, 256, 0, stream>>>(x, E, coln, idx, cnts, dwT);
    k_stats<<<1, 256, 0, stream>>>(emaC, cnts, out + OUT_CLUS, scal, out + OUT_PERP);
    k_emb<<<(DD * NR_EMB) / 256, 256, 0, stream>>>(emaDw, emaC, cnts, dwT, scal,
                                                   out + OUT_DW, out + OUT_EMB, embT);
    k_gather<<<(NTOT * DD / 4) / 256, 256, 0, stream>>>(x, embT, idx, out + OUT_Q, lpart);
    k_final<<<1, 256, 0, stream>>>(lpart, out + OUT_LOSS);
}

// Round 2
// 682.556 us; speedup vs baseline: 1.4702x; 1.4702x over previous
//
#include <hip/hip_runtime.h>
#include <cstdint>
#include <cstddef>

#define NR_EMB 4096
#define DD 128
#define NTOT 65536   // 32*2048
#define MARGIN 1e-3f

typedef __attribute__((ext_vector_type(8))) short short8;
typedef __attribute__((ext_vector_type(4))) float f32x4;

// ---------------- workspace layout (bytes) ----------------
#define WS_DWT    0u          // float[4096*128] (K-major)
#define WS_CNT    2097152u    // uint[4096]
#define WS_SCAL   2113536u    // float[16]
#define WS_AMBC   2113600u    // int[16]
// memset range: [0, 2113664)
#define WS_COLN   2113664u    // float[4096]
#define WS_IDX    2130048u    // int[65536]
#define WS_EMBT   2392192u    // float[4096*128]
#define WS_LPART  4489344u    // float[8192]
#define WS_ETH    4522112u    // ushort[4096*128] bf16 hi, swizzled
#define WS_ETL    5570688u    // ushort[4096*128] bf16 lo, swizzled
#define WS_ET32   6619264u    // float[4096*128]  fp32 transposed
#define WS_AMBL   8716416u    // int[65536]
// total ~8.98 MB

// ---------------- output layout (floats) ----------------
#define OUT_Q      0u
#define OUT_LOSS   8388608u
#define OUT_PERP   8388609u
#define OUT_EMB    8388610u
#define OUT_CLUS   8912898u
#define OUT_DW     8916994u

__device__ __forceinline__ unsigned short f2bf(float f) {
    unsigned u = __float_as_uint(f);
    return (unsigned short)((u + 0x7FFFu + ((u >> 16) & 1u)) >> 16);
}
__device__ __forceinline__ float bf2f(unsigned short h) {
    return __uint_as_float(((unsigned)h) << 16);
}

// ---- prep: transpose E -> bf16 hi/lo (swizzled) + fp32 copy + colnorm ----
__global__ __launch_bounds__(256) void k_prep_e(const float* __restrict__ E,
                                                unsigned short* __restrict__ EtHb,
                                                unsigned short* __restrict__ EtLb,
                                                float* __restrict__ Et32,
                                                float* __restrict__ coln) {
    __shared__ float Es[128][65];
    const int tid = threadIdx.x;
    const int k0  = blockIdx.x * 64;
    #pragma unroll
    for (int i = 0; i < 32; ++i) {
        int e = i * 256 + tid;
        int d = e >> 6, kc = e & 63;
        Es[d][kc] = E[(size_t)d * NR_EMB + k0 + kc];
    }
    __syncthreads();
    const int kc = tid >> 2, q = tid & 3;
    const int k = k0 + kc;
    const unsigned sw = (unsigned)((k & 7) << 3);
    float cs = 0.f;
    for (int i = 0; i < 32; ++i) {
        int d = q * 32 + i;
        float v = Es[d][kc];
        cs = fmaf(v, v, cs);
        unsigned short h = f2bf(v);
        unsigned short l = f2bf(v - bf2f(h));
        Et32[(size_t)k * DD + d] = v;
        EtHb[(size_t)k * DD + (d ^ sw)] = h;
        EtLb[(size_t)k * DD + (d ^ sw)] = l;
    }
    cs += __shfl_xor(cs, 1);
    cs += __shfl_xor(cs, 2);
    if (q == 0) coln[k] = cs;
}

__device__ __forceinline__ void mrg(float& b1, int& i1, float& b2,
                                    float ob1, int oi1, float ob2) {
    bool take = (ob1 < b1) || (ob1 == b1 && oi1 < i1);
    float loser = take ? b1 : ob1;
    b2 = fminf(fminf(b2, ob2), loser);
    if (take) { b1 = ob1; i1 = oi1; }
}

// ---- main distance/argmin kernel: bf16-split MFMA screening ----
__global__ __launch_bounds__(256, 2) void k_dist(const float* __restrict__ x,
                                                 const unsigned short* __restrict__ EtHb,
                                                 const unsigned short* __restrict__ EtLb,
                                                 const float* __restrict__ coln,
                                                 int* __restrict__ idx_out,
                                                 int* __restrict__ ambCnt,
                                                 int* __restrict__ ambList) {
    __shared__ char lds[65536];   // [buf][EtH 16K | EtL 16K] x2

    const int tid  = threadIdx.x;
    const int lane = tid & 63;
    const int w    = tid >> 6;
    const int n0   = blockIdx.x * 64;
    const int rowbase = (w >> 1) * 32;   // code-half within tile
    const int shalf   = (w & 1) * 32;    // sample-half

    // stage tile kt into buffer b
    auto stage = [&](int kt, int b) {
        const char* gH = (const char*)EtHb + (size_t)kt * 16384;
        const char* gL = (const char*)EtLb + (size_t)kt * 16384;
        char* lH = lds + b * 32768;
        char* lL = lH + 16384;
        int off = tid * 16;
        #pragma unroll
        for (int j = 0; j < 4; ++j) {
            __builtin_amdgcn_global_load_lds(
                (const __attribute__((address_space(1))) unsigned int*)(gH + off + j * 4096),
                (__attribute__((address_space(3))) unsigned int*)(lH + off + j * 4096), 16, 0, 0);
            __builtin_amdgcn_global_load_lds(
                (const __attribute__((address_space(1))) unsigned int*)(gL + off + j * 4096),
                (__attribute__((address_space(3))) unsigned int*)(lL + off + j * 4096), 16, 0, 0);
        }
    };

    stage(0, 0);

    // ---- A fragments (x hi/lo) in registers for the whole K sweep ----
    short8 ah[2][4], al[2][4];
    #pragma unroll
    for (int m = 0; m < 2; ++m) {
        int samp = n0 + shalf + m * 16 + (lane & 15);
        const float* xp = x + (size_t)samp * DD + ((lane >> 4) * 8);
        #pragma unroll
        for (int t = 0; t < 4; ++t) {
            float4 f0 = *(const float4*)(xp + t * 32);
            float4 f1 = *(const float4*)(xp + t * 32 + 4);
            float fv[8] = {f0.x, f0.y, f0.z, f0.w, f1.x, f1.y, f1.z, f1.w};
            short8 h, l;
            #pragma unroll
            for (int j = 0; j < 8; ++j) {
                unsigned short hh = f2bf(fv[j]);
                h[j] = (short)hh;
                l[j] = (short)f2bf(fv[j] - bf2f(hh));
            }
            ah[m][t] = h;
            al[m][t] = l;
        }
    }
    __syncthreads();

    float b1[2][2][4], b2[2][2][4];
    int   kb[2][2][4];
    #pragma unroll
    for (int m = 0; m < 2; ++m)
        #pragma unroll
        for (int n = 0; n < 2; ++n)
            #pragma unroll
            for (int r = 0; r < 4; ++r) { b1[m][n][r] = 3.4e38f; b2[m][n][r] = 3.4e38f; kb[m][n][r] = 0; }

    int buf = 0;
    for (int kt = 0; kt < 64; ++kt) {
        if (kt < 63) stage(kt + 1, buf ^ 1);
        float cn0 = coln[kt * 64 + rowbase + (lane & 15)];
        float cn1 = coln[kt * 64 + rowbase + 16 + (lane & 15)];

        const char* lH = lds + buf * 32768;
        const char* lL = lH + 16384;

        f32x4 acc[2][2];
        #pragma unroll
        for (int m = 0; m < 2; ++m)
            #pragma unroll
            for (int n = 0; n < 2; ++n) acc[m][n] = (f32x4){0.f, 0.f, 0.f, 0.f};

        #pragma unroll
        for (int n = 0; n < 2; ++n) {
            int row = rowbase + n * 16 + (lane & 15);
            size_t rb = (size_t)row << 8;
            unsigned swz = (unsigned)((row & 7) << 4);
            #pragma unroll
            for (int t = 0; t < 4; ++t) {
                unsigned coff = ((unsigned)(t * 64 + ((lane >> 4) << 4))) ^ swz;
                short8 bh = *(const short8*)(lH + rb + coff);
                short8 bl = *(const short8*)(lL + rb + coff);
                acc[0][n] = __builtin_amdgcn_mfma_f32_16x16x32_bf16(ah[0][t], bh, acc[0][n], 0, 0, 0);
                acc[1][n] = __builtin_amdgcn_mfma_f32_16x16x32_bf16(ah[1][t], bh, acc[1][n], 0, 0, 0);
                acc[0][n] = __builtin_amdgcn_mfma_f32_16x16x32_bf16(al[0][t], bh, acc[0][n], 0, 0, 0);
                acc[1][n] = __builtin_amdgcn_mfma_f32_16x16x32_bf16(al[1][t], bh, acc[1][n], 0, 0, 0);
                acc[0][n] = __builtin_amdgcn_mfma_f32_16x16x32_bf16(ah[0][t], bl, acc[0][n], 0, 0, 0);
                acc[1][n] = __builtin_amdgcn_mfma_f32_16x16x32_bf16(ah[1][t], bl, acc[1][n], 0, 0, 0);
            }
        }

        // epilogue: screened dist = ||e||^2 - 2*x.e  (xnorm is per-sample constant)
        #pragma unroll
        for (int m = 0; m < 2; ++m) {
            #pragma unroll
            for (int n = 0; n < 2; ++n) {
                float cn = n ? cn1 : cn0;
                #pragma unroll
                for (int r = 0; r < 4; ++r) {
                    float d = fmaf(-2.f, acc[m][n][r], cn);
                    bool lt = d < b1[m][n][r];
                    float t2 = lt ? b1[m][n][r] : d;
                    b2[m][n][r] = fminf(b2[m][n][r], t2);
                    b1[m][n][r] = lt ? d : b1[m][n][r];
                    kb[m][n][r] = lt ? kt : kb[m][n][r];
                }
            }
        }
        __syncthreads();
        buf ^= 1;
    }

    // ---- reduce: in-lane (n), cross-lane (16), cross-wave (code halves) ----
    float* sb1 = (float*)lds;
    int*   si1 = (int*)(lds + 512);
    float* sb2 = (float*)(lds + 1024);

    #pragma unroll
    for (int m = 0; m < 2; ++m) {
        #pragma unroll
        for (int r = 0; r < 4; ++r) {
            float B1 = b1[m][0][r];
            int   I1 = kb[m][0][r] * 64 + rowbase + (lane & 15);
            float B2 = b2[m][0][r];
            mrg(B1, I1, B2, b1[m][1][r], kb[m][1][r] * 64 + rowbase + 16 + (lane & 15), b2[m][1][r]);
            #pragma unroll
            for (int msk = 1; msk < 16; msk <<= 1) {
                float ob1 = __shfl_xor(B1, msk);
                int   oi1 = __shfl_xor(I1, msk);
                float ob2 = __shfl_xor(B2, msk);
                mrg(B1, I1, B2, ob1, oi1, ob2);
            }
            if ((lane & 15) == 0) {
                int sl = shalf + m * 16 + ((lane >> 4) << 2) + r;
                int ch = w >> 1;
                sb1[ch * 64 + sl] = B1;
                si1[ch * 64 + sl] = I1;
                sb2[ch * 64 + sl] = B2;
            }
        }
    }
    __syncthreads();
    if (tid < 64) {
        float B1 = sb1[tid]; int I1 = si1[tid]; float B2 = sb2[tid];
        mrg(B1, I1, B2, sb1[64 + tid], si1[64 + tid], sb2[64 + tid]);
        idx_out[n0 + tid] = I1;
        if (B2 - B1 < MARGIN) {
            int p = atomicAdd(ambCnt, 1);
            ambList[p] = n0 + tid;
        }
    }
}

// ---- exact fp32 rescore of ambiguous samples (full 4096 scan) ----
__global__ __launch_bounds__(256) void k_rescore(const float* __restrict__ x,
                                                 const float* __restrict__ Et32,
                                                 const float* __restrict__ coln,
                                                 const int* __restrict__ ambCnt,
                                                 const int* __restrict__ ambList,
                                                 int* __restrict__ idx_out) {
    __shared__ float xr[128];
    __shared__ float rb[256];
    __shared__ int   ri[256];
    const int tid = threadIdx.x;
    const int cnt = *ambCnt;
    for (int e = blockIdx.x; e < cnt; e += gridDim.x) {
        int s = ambList[e];
        __syncthreads();
        if (tid < 32) *(float4*)&xr[tid * 4] = *(const float4*)&x[(size_t)s * DD + tid * 4];
        __syncthreads();
        float xn = 0.f;
        for (int d = 0; d < DD; ++d) xn = fmaf(xr[d], xr[d], xn);
        float best = 3.4e38f;
        int   bi = 0;
        for (int i = 0; i < 16; ++i) {
            int k = tid + i * 256;
            const float* ep = &Et32[(size_t)k * DD];
            float dot = 0.f;
            for (int d = 0; d < DD; ++d) dot = fmaf(xr[d], ep[d], dot);
            float dist = (xn - 2.0f * dot) + coln[k];
            if (dist < best || (dist == best && k < bi)) { best = dist; bi = k; }
        }
        rb[tid] = best; ri[tid] = bi;
        __syncthreads();
        for (int off = 128; off > 0; off >>= 1) {
            if (tid < off) {
                float ob = rb[tid + off]; int oi = ri[tid + off];
                if (ob < rb[tid] || (ob == rb[tid] && oi < ri[tid])) { rb[tid] = ob; ri[tid] = oi; }
            }
            __syncthreads();
        }
        if (tid == 0) idx_out[s] = ri[0];
    }
}

// ---- scatter x into dwT + counts (after final idx) ----
__global__ __launch_bounds__(256) void k_scatter(const float* __restrict__ x,
                                                 const int* __restrict__ idx,
                                                 float* __restrict__ dwT,
                                                 unsigned int* __restrict__ counts) {
    const int tid = threadIdx.x;
    const int n0 = blockIdx.x * 64;
    const int d = tid & 127, half = tid >> 7;
    for (int s = half; s < 64; s += 2) {
        int k = idx[n0 + s];
        atomicAdd(&dwT[(size_t)k * DD + d], x[(size_t)(n0 + s) * DD + d]);
    }
    if (tid < 64) atomicAdd(&counts[idx[n0 + tid]], 1u);
}

__global__ __launch_bounds__(256) void k_stats(const float* __restrict__ emaC,
                                               const unsigned int* __restrict__ counts,
                                               float* __restrict__ outC,
                                               float* __restrict__ scal,
                                               float* __restrict__ outPerp) {
    __shared__ float rs[256], rp[256];
    int tid = threadIdx.x;
    float sc = 0.f, sp = 0.f;
    for (int k = tid; k < NR_EMB; k += 256) {
        float cnt = (float)counts[k];
        float nc  = emaC[k] * 0.99f + cnt * 0.01f;
        outC[k] = nc;
        sc += nc;
        float p = cnt * (1.0f / 65536.0f);
        sp += p * logf(p + 1e-10f);
    }
    rs[tid] = sc; rp[tid] = sp;
    __syncthreads();
    for (int off = 128; off > 0; off >>= 1) {
        if (tid < off) { rs[tid] += rs[tid + off]; rp[tid] += rp[tid + off]; }
        __syncthreads();
    }
    if (tid == 0) {
        scal[0] = rs[0];
        outPerp[0] = expf(-rp[0]);
    }
}

__global__ __launch_bounds__(256) void k_emb(const float* __restrict__ emaDw,
                                             const float* __restrict__ emaC,
                                             const unsigned int* __restrict__ counts,
                                             const float* __restrict__ dwT,
                                             const float* __restrict__ scal,
                                             float* __restrict__ outDw,
                                             float* __restrict__ outEmb,
                                             float* __restrict__ embT) {
    int g = blockIdx.x * 256 + threadIdx.x;
    int d = g >> 12;
    int k = g & 4095;
    float dw  = emaDw[g] * 0.99f + dwT[k * DD + d] * 0.01f;
    float cnt = (float)counts[k];
    float nc  = emaC[k] * 0.99f + cnt * 0.01f;
    float n   = scal[0];
    float denom = n * (nc + 1e-5f) / (n + 0.04096f);
    float e = dw / denom;
    outDw[g]  = dw;
    outEmb[g] = e;
    embT[k * DD + d] = e;
}

__global__ __launch_bounds__(256) void k_gather(const float* __restrict__ x,
                                                const float* __restrict__ embT,
                                                const int* __restrict__ idx,
                                                float* __restrict__ q,
                                                float* __restrict__ lpart) {
    __shared__ float wred[4];
    int g = blockIdx.x * 256 + threadIdx.x;
    int n = g >> 5;
    int c = g & 31;
    int k = idx[n];
    float4 e  = *reinterpret_cast<const float4*>(&embT[(size_t)k * DD + c * 4]);
    float4 xv = *reinterpret_cast<const float4*>(&x[(size_t)n * DD + c * 4]);
    float dx = e.x - xv.x, dy = e.y - xv.y, dz = e.z - xv.z, dw = e.w - xv.w;
    float4 qo;
    qo.x = xv.x + dx; qo.y = xv.y + dy; qo.z = xv.z + dz; qo.w = xv.w + dw;
    *reinterpret_cast<float4*>(&q[(size_t)n * DD + c * 4]) = qo;
    float s = dx * dx + dy * dy + dz * dz + dw * dw;
    #pragma unroll
    for (int off = 32; off > 0; off >>= 1) s += __shfl_down(s, off);
    if ((threadIdx.x & 63) == 0) wred[threadIdx.x >> 6] = s;
    __syncthreads();
    if (threadIdx.x == 0)
        lpart[blockIdx.x] = wred[0] + wred[1] + wred[2] + wred[3];
}

__global__ __launch_bounds__(256) void k_final(const float* __restrict__ lpart,
                                               float* __restrict__ outLoss) {
    __shared__ float r[256];
    float s = 0.f;
    for (int i = threadIdx.x; i < 8192; i += 256) s += lpart[i];
    r[threadIdx.x] = s;
    __syncthreads();
    for (int off = 128; off > 0; off >>= 1) {
        if (threadIdx.x < off) r[threadIdx.x] += r[threadIdx.x + off];
        __syncthreads();
    }
    if (threadIdx.x == 0) outLoss[0] = r[0] * (1.0f / 8388608.0f);
}

extern "C" void kernel_launch(void* const* d_in, const int* in_sizes, int n_in,
                              void* d_out, int out_size, void* d_ws, size_t ws_size,
                              hipStream_t stream) {
    const float* x     = (const float*)d_in[0];
    const float* E     = (const float*)d_in[1];
    const float* emaC  = (const float*)d_in[2];
    const float* emaDw = (const float*)d_in[3];
    float* out = (float*)d_out;
    char*  ws  = (char*)d_ws;

    float*          dwT   = (float*)(ws + WS_DWT);
    unsigned int*   cnts  = (unsigned int*)(ws + WS_CNT);
    float*          scal  = (float*)(ws + WS_SCAL);
    int*            ambC  = (int*)(ws + WS_AMBC);
    float*          coln  = (float*)(ws + WS_COLN);
    int*            idx   = (int*)(ws + WS_IDX);
    float*          embT  = (float*)(ws + WS_EMBT);
    float*          lpart = (float*)(ws + WS_LPART);
    unsigned short* EtHb  = (unsigned short*)(ws + WS_ETH);
    unsigned short* EtLb  = (unsigned short*)(ws + WS_ETL);
    float*          Et32  = (float*)(ws + WS_ET32);
    int*            ambL  = (int*)(ws + WS_AMBL);

    hipMemsetAsync(ws, 0, WS_AMBC + 64u, stream);

    k_prep_e<<<64, 256, 0, stream>>>(E, EtHb, EtLb, Et32, coln);
    k_dist<<<NTOT / 64, 256, 0, stream>>>(x, EtHb, EtLb, coln, idx, ambC, ambL);
    k_rescore<<<128, 256, 0, stream>>>(x, Et32, coln, ambC, ambL, idx);
    k_scatter<<<NTOT / 64, 256, 0, stream>>>(x, idx, dwT, cnts);
    k_stats<<<1, 256, 0, stream>>>(emaC, cnts, out + OUT_CLUS, scal, out + OUT_PERP);
    k_emb<<<(DD * NR_EMB) / 256, 256, 0, stream>>>(emaDw, emaC, cnts, dwT, scal,
                                                   out + OUT_DW, out + OUT_EMB, embT);
    k_gather<<<(NTOT * DD / 4) / 256, 256, 0, stream>>>(x, embT, idx, out + OUT_Q, lpart);
    k_final<<<1, 256, 0, stream>>>(lpart, out + OUT_LOSS);
}

// Round 3
// 554.029 us; speedup vs baseline: 1.8112x; 1.2320x over previous
//
#include <hip/hip_runtime.h>
#include <cstdint>
#include <cstddef>

#define NR_EMB 4096
#define DD 128
#define NTOT 65536   // 32*2048
#define MARGIN 3e-4f
#define RB 8         // rescore batch size

typedef __attribute__((ext_vector_type(8))) short short8;
typedef __attribute__((ext_vector_type(4))) float f32x4;

// ---------------- workspace layout (bytes) ----------------
#define WS_DWT    0u          // float[4096*128] (K-major)
#define WS_CNT    2097152u    // uint[4096]
#define WS_SCAL   2113536u    // float[16]
#define WS_AMBC   2113600u    // int[16]
// memset range: [0, 2113664)
#define WS_COLN   2113664u    // float[4096]
#define WS_IDX    2130048u    // int[65536]
#define WS_EMBT   2392192u    // float[4096*128]
#define WS_LPART  4489344u    // float[8192]
#define WS_ETH    4522112u    // ushort[4096*128] bf16 hi, swizzled
#define WS_ETL    5570688u    // ushort[4096*128] bf16 lo, swizzled
#define WS_AMBL   6619264u    // int[65536]
// total ~6.9 MB

// ---------------- output layout (floats) ----------------
#define OUT_Q      0u
#define OUT_LOSS   8388608u
#define OUT_PERP   8388609u
#define OUT_EMB    8388610u
#define OUT_CLUS   8912898u
#define OUT_DW     8916994u

__device__ __forceinline__ unsigned short f2bf(float f) {
    unsigned u = __float_as_uint(f);
    return (unsigned short)((u + 0x7FFFu + ((u >> 16) & 1u)) >> 16);
}
__device__ __forceinline__ float bf2f(unsigned short h) {
    return __uint_as_float(((unsigned)h) << 16);
}

// ---- prep: transpose E -> bf16 hi/lo (swizzled) + colnorm ----
__global__ __launch_bounds__(256) void k_prep_e(const float* __restrict__ E,
                                                unsigned short* __restrict__ EtHb,
                                                unsigned short* __restrict__ EtLb,
                                                float* __restrict__ coln) {
    __shared__ float Es[128][65];
    const int tid = threadIdx.x;
    const int k0  = blockIdx.x * 64;
    #pragma unroll
    for (int i = 0; i < 32; ++i) {
        int e = i * 256 + tid;
        int d = e >> 6, kc = e & 63;
        Es[d][kc] = E[(size_t)d * NR_EMB + k0 + kc];
    }
    __syncthreads();
    const int kc = tid >> 2, q = tid & 3;
    const int k = k0 + kc;
    const unsigned sw = (unsigned)((k & 7) << 3);
    float cs = 0.f;
    for (int i = 0; i < 32; ++i) {
        int d = q * 32 + i;
        float v = Es[d][kc];
        cs = fmaf(v, v, cs);
        unsigned short h = f2bf(v);
        unsigned short l = f2bf(v - bf2f(h));
        EtHb[(size_t)k * DD + (d ^ sw)] = h;
        EtLb[(size_t)k * DD + (d ^ sw)] = l;
    }
    cs += __shfl_xor(cs, 1);
    cs += __shfl_xor(cs, 2);
    if (q == 0) coln[k] = cs;
}

__device__ __forceinline__ void mrg(float& b1, int& i1, float& b2,
                                    float ob1, int oi1, float ob2) {
    bool take = (ob1 < b1) || (ob1 == b1 && oi1 < i1);
    float loser = take ? b1 : ob1;
    b2 = fminf(fminf(b2, ob2), loser);
    if (take) { b1 = ob1; i1 = oi1; }
}

// ---- main distance/argmin kernel: 4-term bf16-split MFMA screening ----
__global__ __launch_bounds__(256, 2) void k_dist(const float* __restrict__ x,
                                                 const unsigned short* __restrict__ EtHb,
                                                 const unsigned short* __restrict__ EtLb,
                                                 const float* __restrict__ coln,
                                                 int* __restrict__ idx_out,
                                                 int* __restrict__ ambCnt,
                                                 int* __restrict__ ambList) {
    __shared__ char lds[65536];   // [buf][EtH 16K | EtL 16K] x2

    const int tid  = threadIdx.x;
    const int lane = tid & 63;
    const int w    = tid >> 6;
    const int n0   = blockIdx.x * 64;
    const int rowbase = (w >> 1) * 32;   // code-half within tile
    const int shalf   = (w & 1) * 32;    // sample-half

    auto stage = [&](int kt, int b) {
        const char* gH = (const char*)EtHb + (size_t)kt * 16384;
        const char* gL = (const char*)EtLb + (size_t)kt * 16384;
        char* lH = lds + b * 32768;
        char* lL = lH + 16384;
        int off = tid * 16;
        #pragma unroll
        for (int j = 0; j < 4; ++j) {
            __builtin_amdgcn_global_load_lds(
                (const __attribute__((address_space(1))) unsigned int*)(gH + off + j * 4096),
                (__attribute__((address_space(3))) unsigned int*)(lH + off + j * 4096), 16, 0, 0);
            __builtin_amdgcn_global_load_lds(
                (const __attribute__((address_space(1))) unsigned int*)(gL + off + j * 4096),
                (__attribute__((address_space(3))) unsigned int*)(lL + off + j * 4096), 16, 0, 0);
        }
    };

    stage(0, 0);

    // ---- A fragments (x hi/lo) in registers for the whole K sweep ----
    short8 ah[2][4], al[2][4];
    #pragma unroll
    for (int m = 0; m < 2; ++m) {
        int samp = n0 + shalf + m * 16 + (lane & 15);
        const float* xp = x + (size_t)samp * DD + ((lane >> 4) * 8);
        #pragma unroll
        for (int t = 0; t < 4; ++t) {
            float4 f0 = *(const float4*)(xp + t * 32);
            float4 f1 = *(const float4*)(xp + t * 32 + 4);
            float fv[8] = {f0.x, f0.y, f0.z, f0.w, f1.x, f1.y, f1.z, f1.w};
            short8 h, l;
            #pragma unroll
            for (int j = 0; j < 8; ++j) {
                unsigned short hh = f2bf(fv[j]);
                h[j] = (short)hh;
                l[j] = (short)f2bf(fv[j] - bf2f(hh));
            }
            ah[m][t] = h;
            al[m][t] = l;
        }
    }
    __syncthreads();

    float b1[2][2][4], b2[2][2][4];
    int   kb[2][2][4];
    #pragma unroll
    for (int m = 0; m < 2; ++m)
        #pragma unroll
        for (int n = 0; n < 2; ++n)
            #pragma unroll
            for (int r = 0; r < 4; ++r) { b1[m][n][r] = 3.4e38f; b2[m][n][r] = 3.4e38f; kb[m][n][r] = 0; }

    int buf = 0;
    for (int kt = 0; kt < 64; ++kt) {
        if (kt < 63) stage(kt + 1, buf ^ 1);
        float cn0 = coln[kt * 64 + rowbase + (lane & 15)];
        float cn1 = coln[kt * 64 + rowbase + 16 + (lane & 15)];

        const char* lH = lds + buf * 32768;
        const char* lL = lH + 16384;

        f32x4 acc[2][2];
        #pragma unroll
        for (int m = 0; m < 2; ++m)
            #pragma unroll
            for (int n = 0; n < 2; ++n) acc[m][n] = (f32x4){0.f, 0.f, 0.f, 0.f};

        #pragma unroll
        for (int n = 0; n < 2; ++n) {
            int row = rowbase + n * 16 + (lane & 15);
            size_t rb = (size_t)row << 8;
            unsigned swz = (unsigned)((row & 7) << 4);
            #pragma unroll
            for (int t = 0; t < 4; ++t) {
                unsigned coff = ((unsigned)(t * 64 + ((lane >> 4) << 4))) ^ swz;
                short8 bh = *(const short8*)(lH + rb + coff);
                short8 bl = *(const short8*)(lL + rb + coff);
                acc[0][n] = __builtin_amdgcn_mfma_f32_16x16x32_bf16(ah[0][t], bh, acc[0][n], 0, 0, 0);
                acc[1][n] = __builtin_amdgcn_mfma_f32_16x16x32_bf16(ah[1][t], bh, acc[1][n], 0, 0, 0);
                acc[0][n] = __builtin_amdgcn_mfma_f32_16x16x32_bf16(al[0][t], bh, acc[0][n], 0, 0, 0);
                acc[1][n] = __builtin_amdgcn_mfma_f32_16x16x32_bf16(al[1][t], bh, acc[1][n], 0, 0, 0);
                acc[0][n] = __builtin_amdgcn_mfma_f32_16x16x32_bf16(ah[0][t], bl, acc[0][n], 0, 0, 0);
                acc[1][n] = __builtin_amdgcn_mfma_f32_16x16x32_bf16(ah[1][t], bl, acc[1][n], 0, 0, 0);
                acc[0][n] = __builtin_amdgcn_mfma_f32_16x16x32_bf16(al[0][t], bl, acc[0][n], 0, 0, 0);
                acc[1][n] = __builtin_amdgcn_mfma_f32_16x16x32_bf16(al[1][t], bl, acc[1][n], 0, 0, 0);
            }
        }

        #pragma unroll
        for (int m = 0; m < 2; ++m) {
            #pragma unroll
            for (int n = 0; n < 2; ++n) {
                float cn = n ? cn1 : cn0;
                #pragma unroll
                for (int r = 0; r < 4; ++r) {
                    float d = fmaf(-2.f, acc[m][n][r], cn);
                    bool lt = d < b1[m][n][r];
                    float t2 = lt ? b1[m][n][r] : d;
                    b2[m][n][r] = fminf(b2[m][n][r], t2);
                    b1[m][n][r] = lt ? d : b1[m][n][r];
                    kb[m][n][r] = lt ? kt : kb[m][n][r];
                }
            }
        }
        __syncthreads();
        buf ^= 1;
    }

    // ---- reduce: in-lane (n), cross-lane (16), cross-wave (code halves) ----
    float* sb1 = (float*)lds;
    int*   si1 = (int*)(lds + 512);
    float* sb2 = (float*)(lds + 1024);

    #pragma unroll
    for (int m = 0; m < 2; ++m) {
        #pragma unroll
        for (int r = 0; r < 4; ++r) {
            float B1 = b1[m][0][r];
            int   I1 = kb[m][0][r] * 64 + rowbase + (lane & 15);
            float B2 = b2[m][0][r];
            mrg(B1, I1, B2, b1[m][1][r], kb[m][1][r] * 64 + rowbase + 16 + (lane & 15), b2[m][1][r]);
            #pragma unroll
            for (int msk = 1; msk < 16; msk <<= 1) {
                float ob1 = __shfl_xor(B1, msk);
                int   oi1 = __shfl_xor(I1, msk);
                float ob2 = __shfl_xor(B2, msk);
                mrg(B1, I1, B2, ob1, oi1, ob2);
            }
            if ((lane & 15) == 0) {
                int sl = shalf + m * 16 + ((lane >> 4) << 2) + r;
                int ch = w >> 1;
                sb1[ch * 64 + sl] = B1;
                si1[ch * 64 + sl] = I1;
                sb2[ch * 64 + sl] = B2;
            }
        }
    }
    __syncthreads();
    if (tid < 64) {
        float B1 = sb1[tid]; int I1 = si1[tid]; float B2 = sb2[tid];
        mrg(B1, I1, B2, sb1[64 + tid], si1[64 + tid], sb2[64 + tid]);
        idx_out[n0 + tid] = I1;
        if (B2 - B1 < MARGIN) {
            int p = atomicAdd(ambCnt, 1);
            ambList[p] = n0 + tid;
        }
    }
}

// ---- exact fp32 rescore: 8 samples/batch, coalesced E scan ----
__global__ __launch_bounds__(256) void k_rescore(const float* __restrict__ x,
                                                 const float* __restrict__ E,
                                                 const float* __restrict__ coln,
                                                 const int* __restrict__ ambCnt,
                                                 const int* __restrict__ ambList,
                                                 int* __restrict__ idx_out) {
    __shared__ float xs[RB][DD];
    __shared__ float xn[RB];
    __shared__ int   sid[RB];
    __shared__ float rb1[RB][256];
    __shared__ int   ri1[RB][256];

    const int tid = threadIdx.x;
    const int cnt = *ambCnt;
    const int nbatch = (cnt + RB - 1) / RB;

    for (int b = blockIdx.x; b < nbatch; b += gridDim.x) {
        const int e0 = b * RB;
        const int nb = min(RB, cnt - e0);
        __syncthreads();
        if (tid < RB * 32) {
            int e = tid >> 5, c = tid & 31;
            if (e < nb) {
                int s = ambList[e0 + e];
                if (c == 0) sid[e] = s;
                *(float4*)&xs[e][c * 4] = *(const float4*)&x[(size_t)s * DD + c * 4];
            } else {
                float4 z; z.x = z.y = z.z = z.w = 0.f;
                *(float4*)&xs[e][c * 4] = z;
            }
        }
        __syncthreads();
        if (tid < RB) {
            float a = 0.f;
            for (int d = 0; d < DD; ++d) a = fmaf(xs[tid][d], xs[tid][d], a);
            xn[tid] = a;
        }
        __syncthreads();

        float b1[RB]; int i1[RB];
        #pragma unroll
        for (int e = 0; e < RB; ++e) { b1[e] = 3.4e38f; i1[e] = 0; }

        for (int i = 0; i < 16; ++i) {
            const int k = i * 256 + tid;
            float acc[RB];
            #pragma unroll
            for (int e = 0; e < RB; ++e) acc[e] = 0.f;
            const float* Ek = E + k;
            for (int d4 = 0; d4 < 32; ++d4) {
                float4 xv[RB];
                #pragma unroll
                for (int e = 0; e < RB; ++e) xv[e] = *(const float4*)&xs[e][d4 * 4];
                #pragma unroll
                for (int j = 0; j < 4; ++j) {
                    float Ed = Ek[(size_t)(d4 * 4 + j) * NR_EMB];
                    acc[0] = fmaf((&xv[0].x)[j], Ed, acc[0]);
                    acc[1] = fmaf((&xv[1].x)[j], Ed, acc[1]);
                    acc[2] = fmaf((&xv[2].x)[j], Ed, acc[2]);
                    acc[3] = fmaf((&xv[3].x)[j], Ed, acc[3]);
                    acc[4] = fmaf((&xv[4].x)[j], Ed, acc[4]);
                    acc[5] = fmaf((&xv[5].x)[j], Ed, acc[5]);
                    acc[6] = fmaf((&xv[6].x)[j], Ed, acc[6]);
                    acc[7] = fmaf((&xv[7].x)[j], Ed, acc[7]);
                }
            }
            float cn = coln[k];
            #pragma unroll
            for (int e = 0; e < RB; ++e) {
                float dist = (xn[e] - 2.0f * acc[e]) + cn;   // numpy association order
                bool lt = dist < b1[e];                      // k ascending: strict < = first idx
                i1[e] = lt ? k : i1[e];
                b1[e] = lt ? dist : b1[e];
            }
        }

        #pragma unroll
        for (int e = 0; e < RB; ++e) { rb1[e][tid] = b1[e]; ri1[e][tid] = i1[e]; }
        __syncthreads();
        {
            int g = tid >> 5, l = tid & 31;
            float B = rb1[g][l]; int I = ri1[g][l];
            #pragma unroll
            for (int j = 1; j < 8; ++j) {
                float ob = rb1[g][l + 32 * j]; int oi = ri1[g][l + 32 * j];
                if (ob < B || (ob == B && oi < I)) { B = ob; I = oi; }
            }
            #pragma unroll
            for (int m = 1; m < 32; m <<= 1) {
                float ob = __shfl_xor(B, m, 32);
                int   oi = __shfl_xor(I, m, 32);
                if (ob < B || (ob == B && oi < I)) { B = ob; I = oi; }
            }
            if (l == 0 && g < nb) idx_out[sid[g]] = I;
        }
    }
}

// ---- scatter x into dwT + counts (after final idx) ----
__global__ __launch_bounds__(256) void k_scatter(const float* __restrict__ x,
                                                 const int* __restrict__ idx,
                                                 float* __restrict__ dwT,
                                                 unsigned int* __restrict__ counts) {
    const int tid = threadIdx.x;
    const int n0 = blockIdx.x * 64;
    const int d = tid & 127, half = tid >> 7;
    for (int s = half; s < 64; s += 2) {
        int k = idx[n0 + s];
        atomicAdd(&dwT[(size_t)k * DD + d], x[(size_t)(n0 + s) * DD + d]);
    }
    if (tid < 64) atomicAdd(&counts[idx[n0 + tid]], 1u);
}

__global__ __launch_bounds__(256) void k_stats(const float* __restrict__ emaC,
                                               const unsigned int* __restrict__ counts,
                                               float* __restrict__ outC,
                                               float* __restrict__ scal,
                                               float* __restrict__ outPerp) {
    __shared__ float rs[256], rp[256];
    int tid = threadIdx.x;
    float sc = 0.f, sp = 0.f;
    for (int k = tid; k < NR_EMB; k += 256) {
        float cnt = (float)counts[k];
        float nc  = emaC[k] * 0.99f + cnt * 0.01f;
        outC[k] = nc;
        sc += nc;
        float p = cnt * (1.0f / 65536.0f);
        sp += p * logf(p + 1e-10f);
    }
    rs[tid] = sc; rp[tid] = sp;
    __syncthreads();
    for (int off = 128; off > 0; off >>= 1) {
        if (tid < off) { rs[tid] += rs[tid + off]; rp[tid] += rp[tid + off]; }
        __syncthreads();
    }
    if (tid == 0) {
        scal[0] = rs[0];
        outPerp[0] = expf(-rp[0]);
    }
}

__global__ __launch_bounds__(256) void k_emb(const float* __restrict__ emaDw,
                                             const float* __restrict__ emaC,
                                             const unsigned int* __restrict__ counts,
                                             const float* __restrict__ dwT,
                                             const float* __restrict__ scal,
                                             float* __restrict__ outDw,
                                             float* __restrict__ outEmb,
                                             float* __restrict__ embT) {
    int g = blockIdx.x * 256 + threadIdx.x;
    int d = g >> 12;
    int k = g & 4095;
    float dw  = emaDw[g] * 0.99f + dwT[k * DD + d] * 0.01f;
    float cnt = (float)counts[k];
    float nc  = emaC[k] * 0.99f + cnt * 0.01f;
    float n   = scal[0];
    float denom = n * (nc + 1e-5f) / (n + 0.04096f);
    float e = dw / denom;
    outDw[g]  = dw;
    outEmb[g] = e;
    embT[k * DD + d] = e;
}

__global__ __launch_bounds__(256) void k_gather(const float* __restrict__ x,
                                                const float* __restrict__ embT,
                                                const int* __restrict__ idx,
                                                float* __restrict__ q,
                                                float* __restrict__ lpart) {
    __shared__ float wred[4];
    int g = blockIdx.x * 256 + threadIdx.x;
    int n = g >> 5;
    int c = g & 31;
    int k = idx[n];
    float4 e  = *reinterpret_cast<const float4*>(&embT[(size_t)k * DD + c * 4]);
    float4 xv = *reinterpret_cast<const float4*>(&x[(size_t)n * DD + c * 4]);
    float dx = e.x - xv.x, dy = e.y - xv.y, dz = e.z - xv.z, dw = e.w - xv.w;
    float4 qo;
    qo.x = xv.x + dx; qo.y = xv.y + dy; qo.z = xv.z + dz; qo.w = xv.w + dw;
    *reinterpret_cast<float4*>(&q[(size_t)n * DD + c * 4]) = qo;
    float s = dx * dx + dy * dy + dz * dz + dw * dw;
    #pragma unroll
    for (int off = 32; off > 0; off >>= 1) s += __shfl_down(s, off);
    if ((threadIdx.x & 63) == 0) wred[threadIdx.x >> 6] = s;
    __syncthreads();
    if (threadIdx.x == 0)
        lpart[blockIdx.x] = wred[0] + wred[1] + wred[2] + wred[3];
}

__global__ __launch_bounds__(256) void k_final(const float* __restrict__ lpart,
                                               float* __restrict__ outLoss) {
    __shared__ float r[256];
    float s = 0.f;
    for (int i = threadIdx.x; i < 8192; i += 256) s += lpart[i];
    r[threadIdx.x] = s;
    __syncthreads();
    for (int off = 128; off > 0; off >>= 1) {
        if (threadIdx.x < off) r[threadIdx.x] += r[threadIdx.x + off];
        __syncthreads();
    }
    if (threadIdx.x == 0) outLoss[0] = r[0] * (1.0f / 8388608.0f);
}

extern "C" void kernel_launch(void* const* d_in, const int* in_sizes, int n_in,
                              void* d_out, int out_size, void* d_ws, size_t ws_size,
                              hipStream_t stream) {
    const float* x     = (const float*)d_in[0];
    const float* E     = (const float*)d_in[1];
    const float* emaC  = (const float*)d_in[2];
    const float* emaDw = (const float*)d_in[3];
    float* out = (float*)d_out;
    char*  ws  = (char*)d_ws;

    float*          dwT   = (float*)(ws + WS_DWT);
    unsigned int*   cnts  = (unsigned int*)(ws + WS_CNT);
    float*          scal  = (float*)(ws + WS_SCAL);
    int*            ambC  = (int*)(ws + WS_AMBC);
    float*          coln  = (float*)(ws + WS_COLN);
    int*            idx   = (int*)(ws + WS_IDX);
    float*          embT  = (float*)(ws + WS_EMBT);
    float*          lpart = (float*)(ws + WS_LPART);
    unsigned short* EtHb  = (unsigned short*)(ws + WS_ETH);
    unsigned short* EtLb  = (unsigned short*)(ws + WS_ETL);
    int*            ambL  = (int*)(ws + WS_AMBL);

    hipMemsetAsync(ws, 0, WS_AMBC + 64u, stream);

    k_prep_e<<<64, 256, 0, stream>>>(E, EtHb, EtLb, coln);
    k_dist<<<NTOT / 64, 256, 0, stream>>>(x, EtHb, EtLb, coln, idx, ambC, ambL);
    k_rescore<<<512, 256, 0, stream>>>(x, E, coln, ambC, ambL, idx);
    k_scatter<<<NTOT / 64, 256, 0, stream>>>(x, idx, dwT, cnts);
    k_stats<<<1, 256, 0, stream>>>(emaC, cnts, out + OUT_CLUS, scal, out + OUT_PERP);
    k_emb<<<(DD * NR_EMB) / 256, 256, 0, stream>>>(emaDw, emaC, cnts, dwT, scal,
                                                   out + OUT_DW, out + OUT_EMB, embT);
    k_gather<<<(NTOT * DD / 4) / 256, 256, 0, stream>>>(x, embT, idx, out + OUT_Q, lpart);
    k_final<<<1, 256, 0, stream>>>(lpart, out + OUT_LOSS);
}

// Round 4
// 488.328 us; speedup vs baseline: 2.0549x; 1.1345x over previous
//
#include <hip/hip_runtime.h>
#include <cstdint>
#include <cstddef>

#define NR_EMB 4096
#define DD 128
#define NTOT 65536   // 32*2048
#define MARGIN 1e-3f
#define RB 8         // rescore batch size

typedef __attribute__((ext_vector_type(8))) short short8;
typedef __attribute__((ext_vector_type(4))) float f32x4;

// ---------------- workspace layout (bytes) ----------------
#define WS_CNT    0u          // uint[4096]
#define WS_SCAL   16384u      // float[16]
#define WS_AMBC   16448u      // int[16]
// memset range: [0, 16512)
#define WS_COLN   16512u      // float[4096]
#define WS_IDX    32896u      // int[65536]
#define WS_EMBT   295040u     // float[4096*128]
#define WS_LPART  2392192u    // float[8192]
#define WS_ETH    2424960u    // ushort[4096*128] bf16 hi, swizzled
#define WS_ETL    3473536u    // ushort[4096*128] bf16 lo, swizzled
#define WS_AMBL   4522112u    // int[65536]
#define WS_OFF    4784256u    // int[4096]
#define WS_CUR    4800640u    // int[4096]
#define WS_BKT    4817024u    // int[65536]
#define WS_DWT    5079168u    // float[4096*128]
// total 7,176,320 bytes

// ---------------- output layout (floats) ----------------
#define OUT_Q      0u
#define OUT_LOSS   8388608u
#define OUT_PERP   8388609u
#define OUT_EMB    8388610u
#define OUT_CLUS   8912898u
#define OUT_DW     8916994u

__device__ __forceinline__ unsigned short f2bf(float f) {
    unsigned u = __float_as_uint(f);
    return (unsigned short)((u + 0x7FFFu + ((u >> 16) & 1u)) >> 16);
}
__device__ __forceinline__ float bf2f(unsigned short h) {
    return __uint_as_float(((unsigned)h) << 16);
}

// ---- prep: transpose E -> bf16 hi/lo (swizzled) + colnorm ----
__global__ __launch_bounds__(256) void k_prep_e(const float* __restrict__ E,
                                                unsigned short* __restrict__ EtHb,
                                                unsigned short* __restrict__ EtLb,
                                                float* __restrict__ coln) {
    __shared__ float Es[128][65];
    const int tid = threadIdx.x;
    const int k0  = blockIdx.x * 64;
    #pragma unroll
    for (int i = 0; i < 32; ++i) {
        int e = i * 256 + tid;
        int d = e >> 6, kc = e & 63;
        Es[d][kc] = E[(size_t)d * NR_EMB + k0 + kc];
    }
    __syncthreads();
    const int kc = tid >> 2, q = tid & 3;
    const int k = k0 + kc;
    const unsigned sw = (unsigned)((k & 7) << 3);
    float cs = 0.f;
    for (int i = 0; i < 32; ++i) {
        int d = q * 32 + i;
        float v = Es[d][kc];
        cs = fmaf(v, v, cs);
        unsigned short h = f2bf(v);
        unsigned short l = f2bf(v - bf2f(h));
        EtHb[(size_t)k * DD + (d ^ sw)] = h;
        EtLb[(size_t)k * DD + (d ^ sw)] = l;
    }
    cs += __shfl_xor(cs, 1);
    cs += __shfl_xor(cs, 2);
    if (q == 0) coln[k] = cs;
}

__device__ __forceinline__ void mrg(float& b1, int& i1, float& b2,
                                    float ob1, int oi1, float ob2) {
    bool take = (ob1 < b1) || (ob1 == b1 && oi1 < i1);
    float loser = take ? b1 : ob1;
    b2 = fminf(fminf(b2, ob2), loser);
    if (take) { b1 = ob1; i1 = oi1; }
}

// ---- main distance/argmin kernel: 3-term bf16-split MFMA, 128 samples/block ----
__global__ __launch_bounds__(256, 2) void k_dist(const float* __restrict__ x,
                                                 const unsigned short* __restrict__ EtHb,
                                                 const unsigned short* __restrict__ EtLb,
                                                 const float* __restrict__ coln,
                                                 int* __restrict__ idx_out,
                                                 int* __restrict__ ambCnt,
                                                 int* __restrict__ ambList) {
    __shared__ char lds[65536];   // [buf][EtH 16K | EtL 16K] x2

    const int tid  = threadIdx.x;
    const int lane = tid & 63;
    const int w    = tid >> 6;
    const int n0   = blockIdx.x * 128;
    const int rowbase = (w >> 1) * 32;   // code-half within tile
    const int shalf   = (w & 1) * 64;    // sample-half

    auto stage = [&](int kt, int b) {
        const char* gH = (const char*)EtHb + (size_t)kt * 16384;
        const char* gL = (const char*)EtLb + (size_t)kt * 16384;
        char* lH = lds + b * 32768;
        char* lL = lH + 16384;
        int off = tid * 16;
        #pragma unroll
        for (int j = 0; j < 4; ++j) {
            __builtin_amdgcn_global_load_lds(
                (const __attribute__((address_space(1))) unsigned int*)(gH + off + j * 4096),
                (__attribute__((address_space(3))) unsigned int*)(lH + off + j * 4096), 16, 0, 0);
            __builtin_amdgcn_global_load_lds(
                (const __attribute__((address_space(1))) unsigned int*)(gL + off + j * 4096),
                (__attribute__((address_space(3))) unsigned int*)(lL + off + j * 4096), 16, 0, 0);
        }
    };

    stage(0, 0);

    // ---- A fragments (x hi/lo) in registers for the whole K sweep: 4 m-groups ----
    short8 ah[4][4], al[4][4];
    #pragma unroll
    for (int m = 0; m < 4; ++m) {
        int samp = n0 + shalf + m * 16 + (lane & 15);
        const float* xp = x + (size_t)samp * DD + ((lane >> 4) * 8);
        #pragma unroll
        for (int t = 0; t < 4; ++t) {
            float4 f0 = *(const float4*)(xp + t * 32);
            float4 f1 = *(const float4*)(xp + t * 32 + 4);
            float fv[8] = {f0.x, f0.y, f0.z, f0.w, f1.x, f1.y, f1.z, f1.w};
            short8 h, l;
            #pragma unroll
            for (int j = 0; j < 8; ++j) {
                unsigned short hh = f2bf(fv[j]);
                h[j] = (short)hh;
                l[j] = (short)f2bf(fv[j] - bf2f(hh));
            }
            ah[m][t] = h;
            al[m][t] = l;
        }
    }
    __syncthreads();

    float b1[4][4], b2[4][4];
    int   kb[4][4];
    #pragma unroll
    for (int m = 0; m < 4; ++m)
        #pragma unroll
        for (int r = 0; r < 4; ++r) { b1[m][r] = 3.4e38f; b2[m][r] = 3.4e38f; kb[m][r] = 0; }

    int buf = 0;
    for (int kt = 0; kt < 64; ++kt) {
        if (kt < 63) stage(kt + 1, buf ^ 1);
        const char* lH = lds + buf * 32768;
        const char* lL = lH + 16384;

        #pragma unroll
        for (int n = 0; n < 2; ++n) {
            int row = rowbase + n * 16 + (lane & 15);
            size_t rbo = (size_t)row << 8;
            unsigned swz = (unsigned)((row & 7) << 4);
            float cn = coln[kt * 64 + row];
            int enc = kt * 2 + n;

            f32x4 acc[4];
            #pragma unroll
            for (int m = 0; m < 4; ++m) acc[m] = (f32x4){0.f, 0.f, 0.f, 0.f};

            #pragma unroll
            for (int t = 0; t < 4; ++t) {
                unsigned coff = ((unsigned)(t * 64 + ((lane >> 4) << 4))) ^ swz;
                short8 bh = *(const short8*)(lH + rbo + coff);
                short8 bl = *(const short8*)(lL + rbo + coff);
                #pragma unroll
                for (int m = 0; m < 4; ++m) {
                    acc[m] = __builtin_amdgcn_mfma_f32_16x16x32_bf16(ah[m][t], bh, acc[m], 0, 0, 0);
                    acc[m] = __builtin_amdgcn_mfma_f32_16x16x32_bf16(al[m][t], bh, acc[m], 0, 0, 0);
                    acc[m] = __builtin_amdgcn_mfma_f32_16x16x32_bf16(ah[m][t], bl, acc[m], 0, 0, 0);
                }
            }

            #pragma unroll
            for (int m = 0; m < 4; ++m) {
                #pragma unroll
                for (int r = 0; r < 4; ++r) {
                    float d = fmaf(-2.f, acc[m][r], cn);
                    bool lt = d < b1[m][r];
                    float t2 = lt ? b1[m][r] : d;
                    b2[m][r] = fminf(b2[m][r], t2);
                    b1[m][r] = lt ? d : b1[m][r];
                    kb[m][r] = lt ? enc : kb[m][r];
                }
            }
        }
        __syncthreads();
        buf ^= 1;
    }

    // ---- reduce: cross-lane (16 codes/lane-group), then cross-wave code halves ----
    float* sb1 = (float*)lds;
    int*   si1 = (int*)(lds + 1024);
    float* sb2 = (float*)(lds + 2048);

    #pragma unroll
    for (int m = 0; m < 4; ++m) {
        #pragma unroll
        for (int r = 0; r < 4; ++r) {
            float B1 = b1[m][r];
            int   I1 = (kb[m][r] >> 1) * 64 + rowbase + (kb[m][r] & 1) * 16 + (lane & 15);
            float B2 = b2[m][r];
            #pragma unroll
            for (int msk = 1; msk < 16; msk <<= 1) {
                float ob1 = __shfl_xor(B1, msk);
                int   oi1 = __shfl_xor(I1, msk);
                float ob2 = __shfl_xor(B2, msk);
                mrg(B1, I1, B2, ob1, oi1, ob2);
            }
            if ((lane & 15) == 0) {
                int sl = shalf + m * 16 + ((lane >> 4) << 2) + r;   // 0..127
                int ch = w >> 1;
                sb1[ch * 128 + sl] = B1;
                si1[ch * 128 + sl] = I1;
                sb2[ch * 128 + sl] = B2;
            }
        }
    }
    __syncthreads();
    if (tid < 128) {
        float B1 = sb1[tid]; int I1 = si1[tid]; float B2 = sb2[tid];
        mrg(B1, I1, B2, sb1[128 + tid], si1[128 + tid], sb2[128 + tid]);
        idx_out[n0 + tid] = I1;
        if (B2 - B1 < MARGIN) {
            int p = atomicAdd(ambCnt, 1);
            ambList[p] = n0 + tid;
        }
    }
}

// ---- exact fp32 rescore: 8 samples/batch, coalesced E scan ----
__global__ __launch_bounds__(256) void k_rescore(const float* __restrict__ x,
                                                 const float* __restrict__ E,
                                                 const float* __restrict__ coln,
                                                 const int* __restrict__ ambCnt,
                                                 const int* __restrict__ ambList,
                                                 int* __restrict__ idx_out) {
    __shared__ float xs[RB][DD];
    __shared__ float xn[RB];
    __shared__ int   sid[RB];
    __shared__ float rb1[RB][256];
    __shared__ int   ri1[RB][256];

    const int tid = threadIdx.x;
    const int cnt = *ambCnt;
    const int nbatch = (cnt + RB - 1) / RB;

    for (int b = blockIdx.x; b < nbatch; b += gridDim.x) {
        const int e0 = b * RB;
        const int nb = min(RB, cnt - e0);
        __syncthreads();
        if (tid < RB * 32) {
            int e = tid >> 5, c = tid & 31;
            if (e < nb) {
                int s = ambList[e0 + e];
                if (c == 0) sid[e] = s;
                *(float4*)&xs[e][c * 4] = *(const float4*)&x[(size_t)s * DD + c * 4];
            } else {
                float4 z; z.x = z.y = z.z = z.w = 0.f;
                *(float4*)&xs[e][c * 4] = z;
            }
        }
        __syncthreads();
        if (tid < RB) {
            float a = 0.f;
            for (int d = 0; d < DD; ++d) a = fmaf(xs[tid][d], xs[tid][d], a);
            xn[tid] = a;
        }
        __syncthreads();

        float b1[RB]; int i1[RB];
        #pragma unroll
        for (int e = 0; e < RB; ++e) { b1[e] = 3.4e38f; i1[e] = 0; }

        for (int i = 0; i < 16; ++i) {
            const int k = i * 256 + tid;
            float acc[RB];
            #pragma unroll
            for (int e = 0; e < RB; ++e) acc[e] = 0.f;
            const float* Ek = E + k;
            for (int d4 = 0; d4 < 32; ++d4) {
                float4 xv[RB];
                #pragma unroll
                for (int e = 0; e < RB; ++e) xv[e] = *(const float4*)&xs[e][d4 * 4];
                #pragma unroll
                for (int j = 0; j < 4; ++j) {
                    float Ed = Ek[(size_t)(d4 * 4 + j) * NR_EMB];
                    acc[0] = fmaf((&xv[0].x)[j], Ed, acc[0]);
                    acc[1] = fmaf((&xv[1].x)[j], Ed, acc[1]);
                    acc[2] = fmaf((&xv[2].x)[j], Ed, acc[2]);
                    acc[3] = fmaf((&xv[3].x)[j], Ed, acc[3]);
                    acc[4] = fmaf((&xv[4].x)[j], Ed, acc[4]);
                    acc[5] = fmaf((&xv[5].x)[j], Ed, acc[5]);
                    acc[6] = fmaf((&xv[6].x)[j], Ed, acc[6]);
                    acc[7] = fmaf((&xv[7].x)[j], Ed, acc[7]);
                }
            }
            float cn = coln[k];
            #pragma unroll
            for (int e = 0; e < RB; ++e) {
                float dist = (xn[e] - 2.0f * acc[e]) + cn;   // numpy association order
                bool lt = dist < b1[e];                      // k ascending: strict < = first idx
                i1[e] = lt ? k : i1[e];
                b1[e] = lt ? dist : b1[e];
            }
        }

        #pragma unroll
        for (int e = 0; e < RB; ++e) { rb1[e][tid] = b1[e]; ri1[e][tid] = i1[e]; }
        __syncthreads();
        {
            int g = tid >> 5, l = tid & 31;
            float B = rb1[g][l]; int I = ri1[g][l];
            #pragma unroll
            for (int j = 1; j < 8; ++j) {
                float ob = rb1[g][l + 32 * j]; int oi = ri1[g][l + 32 * j];
                if (ob < B || (ob == B && oi < I)) { B = ob; I = oi; }
            }
            #pragma unroll
            for (int m = 1; m < 32; m <<= 1) {
                float ob = __shfl_xor(B, m, 32);
                int   oi = __shfl_xor(I, m, 32);
                if (ob < B || (ob == B && oi < I)) { B = ob; I = oi; }
            }
            if (l == 0 && g < nb) idx_out[sid[g]] = I;
        }
    }
}

// ---- CSR build: count ----
__global__ __launch_bounds__(256) void k_count(const int* __restrict__ idx,
                                               unsigned int* __restrict__ cnt) {
    for (int i = blockIdx.x * 256 + threadIdx.x; i < NTOT; i += gridDim.x * 256)
        atomicAdd(&cnt[idx[i]], 1u);
}

// ---- fused stats + exclusive prefix (offsets + cursors) ----
__global__ __launch_bounds__(256) void k_statsprefix(const float* __restrict__ emaC,
                                                     const unsigned int* __restrict__ counts,
                                                     float* __restrict__ outC,
                                                     float* __restrict__ scal,
                                                     float* __restrict__ outPerp,
                                                     int* __restrict__ off,
                                                     int* __restrict__ cursor) {
    __shared__ float rs[256], rp[256];
    __shared__ int rc[256];
    const int tid = threadIdx.x;
    float sc = 0.f, sp = 0.f;
    int csum = 0;
    int lc[16];
    #pragma unroll
    for (int j = 0; j < 16; ++j) {
        int k = tid * 16 + j;
        int c = (int)counts[k];
        lc[j] = csum; csum += c;
        float nc = emaC[k] * 0.99f + (float)c * 0.01f;
        outC[k] = nc;
        sc += nc;
        float p = (float)c * (1.0f / 65536.0f);
        sp += p * logf(p + 1e-10f);
    }
    rs[tid] = sc; rp[tid] = sp; rc[tid] = csum;
    __syncthreads();
    for (int o = 1; o < 256; o <<= 1) {   // inclusive scan of rc
        int v = (tid >= o) ? rc[tid - o] : 0;
        __syncthreads();
        rc[tid] += v;
        __syncthreads();
    }
    const int base = rc[tid] - csum;
    #pragma unroll
    for (int j = 0; j < 16; ++j) {
        int k = tid * 16 + j;
        int o = base + lc[j];
        off[k] = o;
        cursor[k] = o;
    }
    for (int o = 128; o > 0; o >>= 1) {
        if (tid < o) { rs[tid] += rs[tid + o]; rp[tid] += rp[tid + o]; }
        __syncthreads();
    }
    if (tid == 0) {
        scal[0] = rs[0];
        outPerp[0] = expf(-rp[0]);
    }
}

// ---- CSR build: fill buckets ----
__global__ __launch_bounds__(256) void k_fill(const int* __restrict__ idx,
                                              int* __restrict__ cursor,
                                              int* __restrict__ bucket) {
    for (int i = blockIdx.x * 256 + threadIdx.x; i < NTOT; i += gridDim.x * 256) {
        int k = idx[i];
        int p = atomicAdd(&cursor[k], 1);
        bucket[p] = i;
    }
}

// ---- per-code dw sum (atomic-free, coalesced) ----
__global__ __launch_bounds__(128) void k_dw(const float* __restrict__ x,
                                            const int* __restrict__ off,
                                            const unsigned int* __restrict__ counts,
                                            const int* __restrict__ bucket,
                                            float* __restrict__ dwT) {
    const int k = blockIdx.x;
    const int d = threadIdx.x;
    const int o = off[k];
    const int c = (int)counts[k];
    float acc = 0.f;
    for (int p = 0; p < c; ++p) {
        int s = bucket[o + p];
        acc += x[(size_t)s * DD + d];
    }
    dwT[(size_t)k * DD + d] = acc;
}

__global__ __launch_bounds__(256) void k_emb(const float* __restrict__ emaDw,
                                             const float* __restrict__ emaC,
                                             const unsigned int* __restrict__ counts,
                                             const float* __restrict__ dwT,
                                             const float* __restrict__ scal,
                                             float* __restrict__ outDw,
                                             float* __restrict__ outEmb,
                                             float* __restrict__ embT) {
    int g = blockIdx.x * 256 + threadIdx.x;
    int d = g >> 12;
    int k = g & 4095;
    float dw  = emaDw[g] * 0.99f + dwT[k * DD + d] * 0.01f;
    float cnt = (float)counts[k];
    float nc  = emaC[k] * 0.99f + cnt * 0.01f;
    float n   = scal[0];
    float denom = n * (nc + 1e-5f) / (n + 0.04096f);
    float e = dw / denom;
    outDw[g]  = dw;
    outEmb[g] = e;
    embT[k * DD + d] = e;
}

__global__ __launch_bounds__(256) void k_gather(const float* __restrict__ x,
                                                const float* __restrict__ embT,
                                                const int* __restrict__ idx,
                                                float* __restrict__ q,
                                                float* __restrict__ lpart) {
    __shared__ float wred[4];
    int g = blockIdx.x * 256 + threadIdx.x;
    int n = g >> 5;
    int c = g & 31;
    int k = idx[n];
    float4 e  = *reinterpret_cast<const float4*>(&embT[(size_t)k * DD + c * 4]);
    float4 xv = *reinterpret_cast<const float4*>(&x[(size_t)n * DD + c * 4]);
    float dx = e.x - xv.x, dy = e.y - xv.y, dz = e.z - xv.z, dw = e.w - xv.w;
    float4 qo;
    qo.x = xv.x + dx; qo.y = xv.y + dy; qo.z = xv.z + dz; qo.w = xv.w + dw;
    *reinterpret_cast<float4*>(&q[(size_t)n * DD + c * 4]) = qo;
    float s = dx * dx + dy * dy + dz * dz + dw * dw;
    #pragma unroll
    for (int off = 32; off > 0; off >>= 1) s += __shfl_down(s, off);
    if ((threadIdx.x & 63) == 0) wred[threadIdx.x >> 6] = s;
    __syncthreads();
    if (threadIdx.x == 0)
        lpart[blockIdx.x] = wred[0] + wred[1] + wred[2] + wred[3];
}

__global__ __launch_bounds__(256) void k_final(const float* __restrict__ lpart,
                                               float* __restrict__ outLoss) {
    __shared__ float r[256];
    float s = 0.f;
    for (int i = threadIdx.x; i < 8192; i += 256) s += lpart[i];
    r[threadIdx.x] = s;
    __syncthreads();
    for (int off = 128; off > 0; off >>= 1) {
        if (threadIdx.x < off) r[threadIdx.x] += r[threadIdx.x + off];
        __syncthreads();
    }
    if (threadIdx.x == 0) outLoss[0] = r[0] * (1.0f / 8388608.0f);
}

extern "C" void kernel_launch(void* const* d_in, const int* in_sizes, int n_in,
                              void* d_out, int out_size, void* d_ws, size_t ws_size,
                              hipStream_t stream) {
    const float* x     = (const float*)d_in[0];
    const float* E     = (const float*)d_in[1];
    const float* emaC  = (const float*)d_in[2];
    const float* emaDw = (const float*)d_in[3];
    float* out = (float*)d_out;
    char*  ws  = (char*)d_ws;

    unsigned int*   cnts  = (unsigned int*)(ws + WS_CNT);
    float*          scal  = (float*)(ws + WS_SCAL);
    int*            ambC  = (int*)(ws + WS_AMBC);
    float*          coln  = (float*)(ws + WS_COLN);
    int*            idx   = (int*)(ws + WS_IDX);
    float*          embT  = (float*)(ws + WS_EMBT);
    float*          lpart = (float*)(ws + WS_LPART);
    unsigned short* EtHb  = (unsigned short*)(ws + WS_ETH);
    unsigned short* EtLb  = (unsigned short*)(ws + WS_ETL);
    int*            ambL  = (int*)(ws + WS_AMBL);
    int*            off   = (int*)(ws + WS_OFF);
    int*            cur   = (int*)(ws + WS_CUR);
    int*            bkt   = (int*)(ws + WS_BKT);
    float*          dwT   = (float*)(ws + WS_DWT);

    hipMemsetAsync(ws, 0, WS_AMBC + 64u, stream);

    k_prep_e<<<64, 256, 0, stream>>>(E, EtHb, EtLb, coln);
    k_dist<<<NTOT / 128, 256, 0, stream>>>(x, EtHb, EtLb, coln, idx, ambC, ambL);
    k_rescore<<<512, 256, 0, stream>>>(x, E, coln, ambC, ambL, idx);
    k_count<<<64, 256, 0, stream>>>(idx, cnts);
    k_statsprefix<<<1, 256, 0, stream>>>(emaC, cnts, out + OUT_CLUS, scal, out + OUT_PERP,
                                         off, cur);
    k_fill<<<64, 256, 0, stream>>>(idx, cur, bkt);
    k_dw<<<NR_EMB, 128, 0, stream>>>(x, off, cnts, bkt, dwT);
    k_emb<<<(DD * NR_EMB) / 256, 256, 0, stream>>>(emaDw, emaC, cnts, dwT, scal,
                                                   out + OUT_DW, out + OUT_EMB, embT);
    k_gather<<<(NTOT * DD / 4) / 256, 256, 0, stream>>>(x, embT, idx, out + OUT_Q, lpart);
    k_final<<<1, 256, 0, stream>>>(lpart, out + OUT_LOSS);
}

// Round 5
// 412.370 us; speedup vs baseline: 2.4335x; 1.1842x over previous
//
#include <hip/hip_runtime.h>
#include <cstdint>
#include <cstddef>

#define NR_EMB 4096
#define DD 128
#define NTOT 65536   // 32*2048
#define MARGIN 3e-4f
#define RB 16        // rescore batch size

typedef __attribute__((ext_vector_type(8))) short short8;
typedef __attribute__((ext_vector_type(4))) float f32x4;

// ---------------- workspace layout (bytes) ----------------
#define WS_CNT    0u          // uint[4096]
#define WS_SCAL   16384u      // float[16]
#define WS_AMBC   16448u      // int[16]
// memset range: [0, 16512)
#define WS_COLN   16512u      // float[4096]
#define WS_IDX    32896u      // int[65536]
#define WS_EMBT   295040u     // float[4096*128]
#define WS_LPART  2392192u    // float[8192]
#define WS_ETH    2424960u    // ushort[4096*128] bf16 hi, swizzled
#define WS_ETL    3473536u    // ushort[4096*128] bf16 lo, swizzled
#define WS_AMBL   4522112u    // int[65536]
#define WS_OFF    4784256u    // int[4096]
#define WS_CUR    4800640u    // int[4096]
#define WS_BKT    4817024u    // int[65536]
#define WS_DWT    5079168u    // float[4096*128]
// total 7,176,320 bytes

// ---------------- output layout (floats) ----------------
#define OUT_Q      0u
#define OUT_LOSS   8388608u
#define OUT_PERP   8388609u
#define OUT_EMB    8388610u
#define OUT_CLUS   8912898u
#define OUT_DW     8916994u

__device__ __forceinline__ unsigned short f2bf(float f) {
    unsigned u = __float_as_uint(f);
    return (unsigned short)((u + 0x7FFFu + ((u >> 16) & 1u)) >> 16);
}
__device__ __forceinline__ float bf2f(unsigned short h) {
    return __uint_as_float(((unsigned)h) << 16);
}

// ---- prep: transpose E -> bf16 hi/lo (swizzled) + colnorm ----
__global__ __launch_bounds__(256) void k_prep_e(const float* __restrict__ E,
                                                unsigned short* __restrict__ EtHb,
                                                unsigned short* __restrict__ EtLb,
                                                float* __restrict__ coln) {
    __shared__ float Es[128][65];
    const int tid = threadIdx.x;
    const int k0  = blockIdx.x * 64;
    #pragma unroll
    for (int i = 0; i < 32; ++i) {
        int e = i * 256 + tid;
        int d = e >> 6, kc = e & 63;
        Es[d][kc] = E[(size_t)d * NR_EMB + k0 + kc];
    }
    __syncthreads();
    const int kc = tid >> 2, q = tid & 3;
    const int k = k0 + kc;
    const unsigned sw = (unsigned)((k & 7) << 3);
    float cs = 0.f;
    for (int i = 0; i < 32; ++i) {
        int d = q * 32 + i;
        float v = Es[d][kc];
        cs = fmaf(v, v, cs);
        unsigned short h = f2bf(v);
        unsigned short l = f2bf(v - bf2f(h));
        EtHb[(size_t)k * DD + (d ^ sw)] = h;
        EtLb[(size_t)k * DD + (d ^ sw)] = l;
    }
    cs += __shfl_xor(cs, 1);
    cs += __shfl_xor(cs, 2);
    if (q == 0) coln[k] = cs;
}

__device__ __forceinline__ void mrg(float& b1, int& i1, float& b2,
                                    float ob1, int oi1, float ob2) {
    bool take = (ob1 < b1) || (ob1 == b1 && oi1 < i1);
    float loser = take ? b1 : ob1;
    b2 = fminf(fminf(b2, ob2), loser);
    if (take) { b1 = ob1; i1 = oi1; }
}

// ---- main distance/argmin kernel: 3-term bf16-split MFMA, 128 samples/block ----
__global__ __launch_bounds__(256, 2) void k_dist(const float* __restrict__ x,
                                                 const unsigned short* __restrict__ EtHb,
                                                 const unsigned short* __restrict__ EtLb,
                                                 const float* __restrict__ coln,
                                                 int* __restrict__ idx_out,
                                                 int* __restrict__ ambCnt,
                                                 int* __restrict__ ambList) {
    __shared__ char lds[65536];   // [buf][EtH 16K | EtL 16K] x2

    const int tid  = threadIdx.x;
    const int lane = tid & 63;
    const int w    = tid >> 6;
    const int n0   = blockIdx.x * 128;
    const int rowbase = (w >> 1) * 32;   // code-half within tile
    const int shalf   = (w & 1) * 64;    // sample-half

    auto stage = [&](int kt, int b) {
        const char* gH = (const char*)EtHb + (size_t)kt * 16384;
        const char* gL = (const char*)EtLb + (size_t)kt * 16384;
        char* lH = lds + b * 32768;
        char* lL = lH + 16384;
        int off = tid * 16;
        #pragma unroll
        for (int j = 0; j < 4; ++j) {
            __builtin_amdgcn_global_load_lds(
                (const __attribute__((address_space(1))) unsigned int*)(gH + off + j * 4096),
                (__attribute__((address_space(3))) unsigned int*)(lH + off + j * 4096), 16, 0, 0);
            __builtin_amdgcn_global_load_lds(
                (const __attribute__((address_space(1))) unsigned int*)(gL + off + j * 4096),
                (__attribute__((address_space(3))) unsigned int*)(lL + off + j * 4096), 16, 0, 0);
        }
    };

    stage(0, 0);

    // ---- A fragments (x hi/lo) in registers for the whole K sweep: 4 m-groups ----
    short8 ah[4][4], al[4][4];
    #pragma unroll
    for (int m = 0; m < 4; ++m) {
        int samp = n0 + shalf + m * 16 + (lane & 15);
        const float* xp = x + (size_t)samp * DD + ((lane >> 4) * 8);
        #pragma unroll
        for (int t = 0; t < 4; ++t) {
            float4 f0 = *(const float4*)(xp + t * 32);
            float4 f1 = *(const float4*)(xp + t * 32 + 4);
            float fv[8] = {f0.x, f0.y, f0.z, f0.w, f1.x, f1.y, f1.z, f1.w};
            short8 h, l;
            #pragma unroll
            for (int j = 0; j < 8; ++j) {
                unsigned short hh = f2bf(fv[j]);
                h[j] = (short)hh;
                l[j] = (short)f2bf(fv[j] - bf2f(hh));
            }
            ah[m][t] = h;
            al[m][t] = l;
        }
    }
    __syncthreads();

    float b1[4][4], b2[4][4];
    int   kb[4][4];
    #pragma unroll
    for (int m = 0; m < 4; ++m)
        #pragma unroll
        for (int r = 0; r < 4; ++r) { b1[m][r] = 3.4e38f; b2[m][r] = 3.4e38f; kb[m][r] = 0; }

    int buf = 0;
    for (int kt = 0; kt < 64; ++kt) {
        if (kt < 63) stage(kt + 1, buf ^ 1);
        const char* lH = lds + buf * 32768;
        const char* lL = lH + 16384;

        #pragma unroll
        for (int n = 0; n < 2; ++n) {
            int row = rowbase + n * 16 + (lane & 15);
            size_t rbo = (size_t)row << 8;
            unsigned swz = (unsigned)((row & 7) << 4);
            float cn = coln[kt * 64 + row];
            int enc = kt * 2 + n;

            f32x4 acc[4];
            #pragma unroll
            for (int m = 0; m < 4; ++m) acc[m] = (f32x4){0.f, 0.f, 0.f, 0.f};

            #pragma unroll
            for (int t = 0; t < 4; ++t) {
                unsigned coff = ((unsigned)(t * 64 + ((lane >> 4) << 4))) ^ swz;
                short8 bh = *(const short8*)(lH + rbo + coff);
                short8 bl = *(const short8*)(lL + rbo + coff);
                #pragma unroll
                for (int m = 0; m < 4; ++m) {
                    acc[m] = __builtin_amdgcn_mfma_f32_16x16x32_bf16(ah[m][t], bh, acc[m], 0, 0, 0);
                    acc[m] = __builtin_amdgcn_mfma_f32_16x16x32_bf16(al[m][t], bh, acc[m], 0, 0, 0);
                    acc[m] = __builtin_amdgcn_mfma_f32_16x16x32_bf16(ah[m][t], bl, acc[m], 0, 0, 0);
                }
            }

            #pragma unroll
            for (int m = 0; m < 4; ++m) {
                #pragma unroll
                for (int r = 0; r < 4; ++r) {
                    float d = fmaf(-2.f, acc[m][r], cn);
                    bool lt = d < b1[m][r];
                    float t2 = lt ? b1[m][r] : d;
                    b2[m][r] = fminf(b2[m][r], t2);
                    b1[m][r] = lt ? d : b1[m][r];
                    kb[m][r] = lt ? enc : kb[m][r];
                }
            }
        }
        __syncthreads();
        buf ^= 1;
    }

    // ---- reduce: cross-lane (16 codes/lane-group), then cross-wave code halves ----
    float* sb1 = (float*)lds;
    int*   si1 = (int*)(lds + 1024);
    float* sb2 = (float*)(lds + 2048);

    #pragma unroll
    for (int m = 0; m < 4; ++m) {
        #pragma unroll
        for (int r = 0; r < 4; ++r) {
            float B1 = b1[m][r];
            int   I1 = (kb[m][r] >> 1) * 64 + rowbase + (kb[m][r] & 1) * 16 + (lane & 15);
            float B2 = b2[m][r];
            #pragma unroll
            for (int msk = 1; msk < 16; msk <<= 1) {
                float ob1 = __shfl_xor(B1, msk);
                int   oi1 = __shfl_xor(I1, msk);
                float ob2 = __shfl_xor(B2, msk);
                mrg(B1, I1, B2, ob1, oi1, ob2);
            }
            if ((lane & 15) == 0) {
                int sl = shalf + m * 16 + ((lane >> 4) << 2) + r;   // 0..127
                int ch = w >> 1;
                sb1[ch * 128 + sl] = B1;
                si1[ch * 128 + sl] = I1;
                sb2[ch * 128 + sl] = B2;
            }
        }
    }
    __syncthreads();
    if (tid < 128) {
        float B1 = sb1[tid]; int I1 = si1[tid]; float B2 = sb2[tid];
        mrg(B1, I1, B2, sb1[128 + tid], si1[128 + tid], sb2[128 + tid]);
        idx_out[n0 + tid] = I1;
        if (B2 - B1 < MARGIN) {
            int p = atomicAdd(ambCnt, 1);
            ambList[p] = n0 + tid;
        }
    }
}

// ---- exact fp32 rescore: 16 samples/batch, 2 k-chunks in flight, prefetched E ----
__global__ __launch_bounds__(256) void k_rescore(const float* __restrict__ x,
                                                 const float* __restrict__ E,
                                                 const float* __restrict__ coln,
                                                 const int* __restrict__ ambCnt,
                                                 const int* __restrict__ ambList,
                                                 int* __restrict__ idx_out) {
    __shared__ float xs[RB][DD];
    __shared__ float xn[RB];
    __shared__ int   sid[RB];
    __shared__ float rb1[RB][256];
    __shared__ int   ri1[RB][256];

    const int tid = threadIdx.x;
    const int cnt = *ambCnt;
    const int nbatch = (cnt + RB - 1) / RB;

    for (int b = blockIdx.x; b < nbatch; b += gridDim.x) {
        const int e0 = b * RB;
        const int nb = min(RB, cnt - e0);
        __syncthreads();
        #pragma unroll
        for (int p = 0; p < 2; ++p) {
            int slot = p * 256 + tid;
            int e = slot >> 5, c = slot & 31;
            if (e < nb) {
                int s = ambList[e0 + e];
                if (c == 0) sid[e] = s;
                *(float4*)&xs[e][c * 4] = *(const float4*)&x[(size_t)s * DD + c * 4];
            } else {
                float4 z; z.x = z.y = z.z = z.w = 0.f;
                *(float4*)&xs[e][c * 4] = z;
            }
        }
        __syncthreads();
        if (tid < RB) {
            float a = 0.f;
            for (int d = 0; d < DD; ++d) a = fmaf(xs[tid][d], xs[tid][d], a);
            xn[tid] = a;
        }
        __syncthreads();

        float b1[RB]; int i1[RB];
        #pragma unroll
        for (int e = 0; e < RB; ++e) { b1[e] = 3.4e38f; i1[e] = 0; }

        for (int i = 0; i < 16; i += 2) {
            const int ka = i * 256 + tid;        // chunk A
            const int kb2 = ka + 256;            // chunk B (next i)
            const float* Ea = E + ka;
            const float* Eb = E + kb2;
            float acca[RB], accb[RB];
            #pragma unroll
            for (int e = 0; e < RB; ++e) { acca[e] = 0.f; accb[e] = 0.f; }

            // prefetch d4=0
            float4 eA, eB;
            eA.x = Ea[0];            eA.y = Ea[(size_t)1 * NR_EMB];
            eA.z = Ea[(size_t)2 * NR_EMB]; eA.w = Ea[(size_t)3 * NR_EMB];
            eB.x = Eb[0];            eB.y = Eb[(size_t)1 * NR_EMB];
            eB.z = Eb[(size_t)2 * NR_EMB]; eB.w = Eb[(size_t)3 * NR_EMB];

            for (int d4 = 0; d4 < 31; ++d4) {
                float4 nA, nB;
                const size_t dn = (size_t)(d4 * 4 + 4) * NR_EMB;
                nA.x = Ea[dn];                    nA.y = Ea[dn + NR_EMB];
                nA.z = Ea[dn + 2 * NR_EMB];       nA.w = Ea[dn + 3 * NR_EMB];
                nB.x = Eb[dn];                    nB.y = Eb[dn + NR_EMB];
                nB.z = Eb[dn + 2 * NR_EMB];       nB.w = Eb[dn + 3 * NR_EMB];
                #pragma unroll
                for (int e = 0; e < RB; ++e) {
                    float4 xv = *(const float4*)&xs[e][d4 * 4];
                    acca[e] = fmaf(xv.x, eA.x, acca[e]);
                    acca[e] = fmaf(xv.y, eA.y, acca[e]);
                    acca[e] = fmaf(xv.z, eA.z, acca[e]);
                    acca[e] = fmaf(xv.w, eA.w, acca[e]);
                    accb[e] = fmaf(xv.x, eB.x, accb[e]);
                    accb[e] = fmaf(xv.y, eB.y, accb[e]);
                    accb[e] = fmaf(xv.z, eB.z, accb[e]);
                    accb[e] = fmaf(xv.w, eB.w, accb[e]);
                }
                eA = nA; eB = nB;
            }
            #pragma unroll
            for (int e = 0; e < RB; ++e) {   // tail d4=31
                float4 xv = *(const float4*)&xs[e][124];
                acca[e] = fmaf(xv.x, eA.x, acca[e]);
                acca[e] = fmaf(xv.y, eA.y, acca[e]);
                acca[e] = fmaf(xv.z, eA.z, acca[e]);
                acca[e] = fmaf(xv.w, eA.w, acca[e]);
                accb[e] = fmaf(xv.x, eB.x, accb[e]);
                accb[e] = fmaf(xv.y, eB.y, accb[e]);
                accb[e] = fmaf(xv.z, eB.z, accb[e]);
                accb[e] = fmaf(xv.w, eB.w, accb[e]);
            }

            const float cna = coln[ka];
            const float cnb = coln[kb2];
            #pragma unroll
            for (int e = 0; e < RB; ++e) {
                float da = (xn[e] - 2.0f * acca[e]) + cna;   // numpy association order
                bool lta = da < b1[e];                       // ka ascending within thread
                i1[e] = lta ? ka : i1[e];
                b1[e] = lta ? da : b1[e];
                float db = (xn[e] - 2.0f * accb[e]) + cnb;
                bool ltb = db < b1[e];
                i1[e] = ltb ? kb2 : i1[e];
                b1[e] = ltb ? db : b1[e];
            }
        }

        #pragma unroll
        for (int e = 0; e < RB; ++e) { rb1[e][tid] = b1[e]; ri1[e][tid] = i1[e]; }
        __syncthreads();
        {
            int g = tid >> 4, l = tid & 15;   // 16 groups x 16 lanes
            float B = rb1[g][l]; int I = ri1[g][l];
            #pragma unroll
            for (int j = 1; j < 16; ++j) {
                float ob = rb1[g][l + 16 * j]; int oi = ri1[g][l + 16 * j];
                if (ob < B || (ob == B && oi < I)) { B = ob; I = oi; }
            }
            #pragma unroll
            for (int m = 1; m < 16; m <<= 1) {
                float ob = __shfl_xor(B, m, 16);
                int   oi = __shfl_xor(I, m, 16);
                if (ob < B || (ob == B && oi < I)) { B = ob; I = oi; }
            }
            if (l == 0 && g < nb) idx_out[sid[g]] = I;
        }
    }
}

// ---- CSR build: count ----
__global__ __launch_bounds__(256) void k_count(const int* __restrict__ idx,
                                               unsigned int* __restrict__ cnt) {
    for (int i = blockIdx.x * 256 + threadIdx.x; i < NTOT; i += gridDim.x * 256)
        atomicAdd(&cnt[idx[i]], 1u);
}

// ---- fused stats + exclusive prefix (offsets + cursors) ----
__global__ __launch_bounds__(256) void k_statsprefix(const float* __restrict__ emaC,
                                                     const unsigned int* __restrict__ counts,
                                                     float* __restrict__ outC,
                                                     float* __restrict__ scal,
                                                     float* __restrict__ outPerp,
                                                     int* __restrict__ off,
                                                     int* __restrict__ cursor) {
    __shared__ float rs[256], rp[256];
    __shared__ int rc[256];
    const int tid = threadIdx.x;
    float sc = 0.f, sp = 0.f;
    int csum = 0;
    int lc[16];
    #pragma unroll
    for (int j = 0; j < 16; ++j) {
        int k = tid * 16 + j;
        int c = (int)counts[k];
        lc[j] = csum; csum += c;
        float nc = emaC[k] * 0.99f + (float)c * 0.01f;
        outC[k] = nc;
        sc += nc;
        float p = (float)c * (1.0f / 65536.0f);
        sp += p * logf(p + 1e-10f);
    }
    rs[tid] = sc; rp[tid] = sp; rc[tid] = csum;
    __syncthreads();
    for (int o = 1; o < 256; o <<= 1) {   // inclusive scan of rc
        int v = (tid >= o) ? rc[tid - o] : 0;
        __syncthreads();
        rc[tid] += v;
        __syncthreads();
    }
    const int base = rc[tid] - csum;
    #pragma unroll
    for (int j = 0; j < 16; ++j) {
        int k = tid * 16 + j;
        int o = base + lc[j];
        off[k] = o;
        cursor[k] = o;
    }
    for (int o = 128; o > 0; o >>= 1) {
        if (tid < o) { rs[tid] += rs[tid + o]; rp[tid] += rp[tid + o]; }
        __syncthreads();
    }
    if (tid == 0) {
        scal[0] = rs[0];
        outPerp[0] = expf(-rp[0]);
    }
}

// ---- CSR build: fill buckets ----
__global__ __launch_bounds__(256) void k_fill(const int* __restrict__ idx,
                                              int* __restrict__ cursor,
                                              int* __restrict__ bucket) {
    for (int i = blockIdx.x * 256 + threadIdx.x; i < NTOT; i += gridDim.x * 256) {
        int k = idx[i];
        int p = atomicAdd(&cursor[k], 1);
        bucket[p] = i;
    }
}

// ---- per-code dw sum (atomic-free, coalesced) ----
__global__ __launch_bounds__(128) void k_dw(const float* __restrict__ x,
                                            const int* __restrict__ off,
                                            const unsigned int* __restrict__ counts,
                                            const int* __restrict__ bucket,
                                            float* __restrict__ dwT) {
    const int k = blockIdx.x;
    const int d = threadIdx.x;
    const int o = off[k];
    const int c = (int)counts[k];
    float acc = 0.f;
    for (int p = 0; p < c; ++p) {
        int s = bucket[o + p];
        acc += x[(size_t)s * DD + d];
    }
    dwT[(size_t)k * DD + d] = acc;
}

__global__ __launch_bounds__(256) void k_emb(const float* __restrict__ emaDw,
                                             const float* __restrict__ emaC,
                                             const unsigned int* __restrict__ counts,
                                             const float* __restrict__ dwT,
                                             const float* __restrict__ scal,
                                             float* __restrict__ outDw,
                                             float* __restrict__ outEmb,
                                             float* __restrict__ embT) {
    int g = blockIdx.x * 256 + threadIdx.x;
    int d = g >> 12;
    int k = g & 4095;
    float dw  = emaDw[g] * 0.99f + dwT[k * DD + d] * 0.01f;
    float cnt = (float)counts[k];
    float nc  = emaC[k] * 0.99f + cnt * 0.01f;
    float n   = scal[0];
    float denom = n * (nc + 1e-5f) / (n + 0.04096f);
    float e = dw / denom;
    outDw[g]  = dw;
    outEmb[g] = e;
    embT[k * DD + d] = e;
}

__global__ __launch_bounds__(256) void k_gather(const float* __restrict__ x,
                                                const float* __restrict__ embT,
                                                const int* __restrict__ idx,
                                                float* __restrict__ q,
                                                float* __restrict__ lpart) {
    __shared__ float wred[4];
    int g = blockIdx.x * 256 + threadIdx.x;
    int n = g >> 5;
    int c = g & 31;
    int k = idx[n];
    float4 e  = *reinterpret_cast<const float4*>(&embT[(size_t)k * DD + c * 4]);
    float4 xv = *reinterpret_cast<const float4*>(&x[(size_t)n * DD + c * 4]);
    float dx = e.x - xv.x, dy = e.y - xv.y, dz = e.z - xv.z, dw = e.w - xv.w;
    float4 qo;
    qo.x = xv.x + dx; qo.y = xv.y + dy; qo.z = xv.z + dz; qo.w = xv.w + dw;
    *reinterpret_cast<float4*>(&q[(size_t)n * DD + c * 4]) = qo;
    float s = dx * dx + dy * dy + dz * dz + dw * dw;
    #pragma unroll
    for (int off = 32; off > 0; off >>= 1) s += __shfl_down(s, off);
    if ((threadIdx.x & 63) == 0) wred[threadIdx.x >> 6] = s;
    __syncthreads();
    if (threadIdx.x == 0)
        lpart[blockIdx.x] = wred[0] + wred[1] + wred[2] + wred[3];
}

__global__ __launch_bounds__(256) void k_final(const float* __restrict__ lpart,
                                               float* __restrict__ outLoss) {
    __shared__ float r[256];
    float s = 0.f;
    for (int i = threadIdx.x; i < 8192; i += 256) s += lpart[i];
    r[threadIdx.x] = s;
    __syncthreads();
    for (int off = 128; off > 0; off >>= 1) {
        if (threadIdx.x < off) r[threadIdx.x] += r[threadIdx.x + off];
        __syncthreads();
    }
    if (threadIdx.x == 0) outLoss[0] = r[0] * (1.0f / 8388608.0f);
}

extern "C" void kernel_launch(void* const* d_in, const int* in_sizes, int n_in,
                              void* d_out, int out_size, void* d_ws, size_t ws_size,
                              hipStream_t stream) {
    const float* x     = (const float*)d_in[0];
    const float* E     = (const float*)d_in[1];
    const float* emaC  = (const float*)d_in[2];
    const float* emaDw = (const float*)d_in[3];
    float* out = (float*)d_out;
    char*  ws  = (char*)d_ws;

    unsigned int*   cnts  = (unsigned int*)(ws + WS_CNT);
    float*          scal  = (float*)(ws + WS_SCAL);
    int*            ambC  = (int*)(ws + WS_AMBC);
    float*          coln  = (float*)(ws + WS_COLN);
    int*            idx   = (int*)(ws + WS_IDX);
    float*          embT  = (float*)(ws + WS_EMBT);
    float*          lpart = (float*)(ws + WS_LPART);
    unsigned short* EtHb  = (unsigned short*)(ws + WS_ETH);
    unsigned short* EtLb  = (unsigned short*)(ws + WS_ETL);
    int*            ambL  = (int*)(ws + WS_AMBL);
    int*            off   = (int*)(ws + WS_OFF);
    int*            cur   = (int*)(ws + WS_CUR);
    int*            bkt   = (int*)(ws + WS_BKT);
    float*          dwT   = (float*)(ws + WS_DWT);

    hipMemsetAsync(ws, 0, WS_AMBC + 64u, stream);

    k_prep_e<<<64, 256, 0, stream>>>(E, EtHb, EtLb, coln);
    k_dist<<<NTOT / 128, 256, 0, stream>>>(x, EtHb, EtLb, coln, idx, ambC, ambL);
    k_rescore<<<512, 256, 0, stream>>>(x, E, coln, ambC, ambL, idx);
    k_count<<<64, 256, 0, stream>>>(idx, cnts);
    k_statsprefix<<<1, 256, 0, stream>>>(emaC, cnts, out + OUT_CLUS, scal, out + OUT_PERP,
                                         off, cur);
    k_fill<<<64, 256, 0, stream>>>(idx, cur, bkt);
    k_dw<<<NR_EMB, 128, 0, stream>>>(x, off, cnts, bkt, dwT);
    k_emb<<<(DD * NR_EMB) / 256, 256, 0, stream>>>(emaDw, emaC, cnts, dwT, scal,
                                                   out + OUT_DW, out + OUT_EMB, embT);
    k_gather<<<(NTOT * DD / 4) / 256, 256, 0, stream>>>(x, embT, idx, out + OUT_Q, lpart);
    k_final<<<1, 256, 0, stream>>>(lpart, out + OUT_LOSS);
}

// Round 6
// 399.258 us; speedup vs baseline: 2.5134x; 1.0328x over previous
//
#include <hip/hip_runtime.h>
#include <cstdint>
#include <cstddef>

#define NR_EMB 4096
#define DD 128
#define NTOT 65536   // 32*2048
#define MARGIN 3e-4f
#define RB 16        // rescore batch size

typedef __attribute__((ext_vector_type(8))) short short8;
typedef __attribute__((ext_vector_type(4))) float f32x4;

// ---------------- workspace layout (bytes) ----------------
#define WS_CNT    0u          // uint[4096]
#define WS_SCAL   16384u      // float[16]
#define WS_AMBC   16448u      // int[16]
// memset range: [0, 16512)
#define WS_COLN   16512u      // float[4096]
#define WS_IDX    32896u      // int[65536]
#define WS_EMBT   295040u     // float[4096*128]
#define WS_LPART  2392192u    // float[8192]
#define WS_ETH    2424960u    // ushort[4096*128] bf16 hi, swizzled
#define WS_ETL    3473536u    // ushort[4096*128] bf16 lo, swizzled
#define WS_AMBL   4522112u    // int[65536]
#define WS_OFF    4784256u    // int[4096]
#define WS_CUR    4800640u    // int[4096]
#define WS_BKT    4817024u    // int[65536]
#define WS_DWT    5079168u    // float[4096*128]
// total 7,176,320 bytes

// ---------------- output layout (floats) ----------------
#define OUT_Q      0u
#define OUT_LOSS   8388608u
#define OUT_PERP   8388609u
#define OUT_EMB    8388610u
#define OUT_CLUS   8912898u
#define OUT_DW     8916994u

__device__ __forceinline__ unsigned short f2bf(float f) {
    unsigned u = __float_as_uint(f);
    return (unsigned short)((u + 0x7FFFu + ((u >> 16) & 1u)) >> 16);
}
__device__ __forceinline__ float bf2f(unsigned short h) {
    return __uint_as_float(((unsigned)h) << 16);
}

// ---- prep: transpose E -> bf16 hi/lo (swizzled) + colnorm ----
__global__ __launch_bounds__(256) void k_prep_e(const float* __restrict__ E,
                                                unsigned short* __restrict__ EtHb,
                                                unsigned short* __restrict__ EtLb,
                                                float* __restrict__ coln) {
    __shared__ float Es[128][65];
    const int tid = threadIdx.x;
    const int k0  = blockIdx.x * 64;
    #pragma unroll
    for (int i = 0; i < 32; ++i) {
        int e = i * 256 + tid;
        int d = e >> 6, kc = e & 63;
        Es[d][kc] = E[(size_t)d * NR_EMB + k0 + kc];
    }
    __syncthreads();
    const int kc = tid >> 2, q = tid & 3;
    const int k = k0 + kc;
    const unsigned sw = (unsigned)((k & 7) << 3);
    float cs = 0.f;
    for (int i = 0; i < 32; ++i) {
        int d = q * 32 + i;
        float v = Es[d][kc];
        cs = fmaf(v, v, cs);
        unsigned short h = f2bf(v);
        unsigned short l = f2bf(v - bf2f(h));
        EtHb[(size_t)k * DD + (d ^ sw)] = h;
        EtLb[(size_t)k * DD + (d ^ sw)] = l;
    }
    cs += __shfl_xor(cs, 1);
    cs += __shfl_xor(cs, 2);
    if (q == 0) coln[k] = cs;
}

__device__ __forceinline__ void mrg(float& b1, int& i1, float& b2,
                                    float ob1, int oi1, float ob2) {
    bool take = (ob1 < b1) || (ob1 == b1 && oi1 < i1);
    float loser = take ? b1 : ob1;
    b2 = fminf(fminf(b2, ob2), loser);
    if (take) { b1 = ob1; i1 = oi1; }
}

// ---- main distance/argmin kernel: 3-term bf16-split MFMA, 128 samples/block ----
__global__ __launch_bounds__(256, 2) void k_dist(const float* __restrict__ x,
                                                 const unsigned short* __restrict__ EtHb,
                                                 const unsigned short* __restrict__ EtLb,
                                                 const float* __restrict__ coln,
                                                 int* __restrict__ idx_out,
                                                 unsigned int* __restrict__ counts,
                                                 int* __restrict__ ambCnt,
                                                 int* __restrict__ ambList) {
    __shared__ char lds[65536];   // [buf][EtH 16K | EtL 16K] x2

    const int tid  = threadIdx.x;
    const int lane = tid & 63;
    const int w    = tid >> 6;
    const int n0   = blockIdx.x * 128;
    const int rowbase = (w >> 1) * 32;   // code-half within tile
    const int shalf   = (w & 1) * 64;    // sample-half

    auto stage = [&](int kt, int b) {
        const char* gH = (const char*)EtHb + (size_t)kt * 16384;
        const char* gL = (const char*)EtLb + (size_t)kt * 16384;
        char* lH = lds + b * 32768;
        char* lL = lH + 16384;
        int off = tid * 16;
        #pragma unroll
        for (int j = 0; j < 4; ++j) {
            __builtin_amdgcn_global_load_lds(
                (const __attribute__((address_space(1))) unsigned int*)(gH + off + j * 4096),
                (__attribute__((address_space(3))) unsigned int*)(lH + off + j * 4096), 16, 0, 0);
            __builtin_amdgcn_global_load_lds(
                (const __attribute__((address_space(1))) unsigned int*)(gL + off + j * 4096),
                (__attribute__((address_space(3))) unsigned int*)(lL + off + j * 4096), 16, 0, 0);
        }
    };

    stage(0, 0);

    // ---- A fragments (x hi/lo) in registers for the whole K sweep: 4 m-groups ----
    short8 ah[4][4], al[4][4];
    #pragma unroll
    for (int m = 0; m < 4; ++m) {
        int samp = n0 + shalf + m * 16 + (lane & 15);
        const float* xp = x + (size_t)samp * DD + ((lane >> 4) * 8);
        #pragma unroll
        for (int t = 0; t < 4; ++t) {
            float4 f0 = *(const float4*)(xp + t * 32);
            float4 f1 = *(const float4*)(xp + t * 32 + 4);
            float fv[8] = {f0.x, f0.y, f0.z, f0.w, f1.x, f1.y, f1.z, f1.w};
            short8 h, l;
            #pragma unroll
            for (int j = 0; j < 8; ++j) {
                unsigned short hh = f2bf(fv[j]);
                h[j] = (short)hh;
                l[j] = (short)f2bf(fv[j] - bf2f(hh));
            }
            ah[m][t] = h;
            al[m][t] = l;
        }
    }
    __syncthreads();

    float b1[4][4], b2[4][4];
    int   kb[4][4];
    #pragma unroll
    for (int m = 0; m < 4; ++m)
        #pragma unroll
        for (int r = 0; r < 4; ++r) { b1[m][r] = 3.4e38f; b2[m][r] = 3.4e38f; kb[m][r] = 0; }

    int buf = 0;
    for (int kt = 0; kt < 64; ++kt) {
        if (kt < 63) stage(kt + 1, buf ^ 1);
        const char* lH = lds + buf * 32768;
        const char* lL = lH + 16384;

        #pragma unroll
        for (int n = 0; n < 2; ++n) {
            int row = rowbase + n * 16 + (lane & 15);
            size_t rbo = (size_t)row << 8;
            unsigned swz = (unsigned)((row & 7) << 4);
            float cn = coln[kt * 64 + row];
            int enc = kt * 2 + n;

            f32x4 acc[4];
            #pragma unroll
            for (int m = 0; m < 4; ++m) acc[m] = (f32x4){0.f, 0.f, 0.f, 0.f};

            __builtin_amdgcn_s_setprio(1);
            #pragma unroll
            for (int t = 0; t < 4; ++t) {
                unsigned coff = ((unsigned)(t * 64 + ((lane >> 4) << 4))) ^ swz;
                short8 bh = *(const short8*)(lH + rbo + coff);
                short8 bl = *(const short8*)(lL + rbo + coff);
                #pragma unroll
                for (int m = 0; m < 4; ++m) {
                    acc[m] = __builtin_amdgcn_mfma_f32_16x16x32_bf16(ah[m][t], bh, acc[m], 0, 0, 0);
                    acc[m] = __builtin_amdgcn_mfma_f32_16x16x32_bf16(al[m][t], bh, acc[m], 0, 0, 0);
                    acc[m] = __builtin_amdgcn_mfma_f32_16x16x32_bf16(ah[m][t], bl, acc[m], 0, 0, 0);
                }
            }
            __builtin_amdgcn_s_setprio(0);

            #pragma unroll
            for (int m = 0; m < 4; ++m) {
                #pragma unroll
                for (int r = 0; r < 4; ++r) {
                    float d = fmaf(-2.f, acc[m][r], cn);
                    bool lt = d < b1[m][r];
                    // top-2 update: new b2 = median(d, b1, b2) given b1<=b2
                    b2[m][r] = __builtin_amdgcn_fmed3f(d, b1[m][r], b2[m][r]);
                    b1[m][r] = fminf(b1[m][r], d);
                    kb[m][r] = lt ? enc : kb[m][r];
                }
            }
        }
        __syncthreads();
        buf ^= 1;
    }

    // ---- reduce: cross-lane (16 codes/lane-group), then cross-wave code halves ----
    float* sb1 = (float*)lds;
    int*   si1 = (int*)(lds + 1024);
    float* sb2 = (float*)(lds + 2048);

    #pragma unroll
    for (int m = 0; m < 4; ++m) {
        #pragma unroll
        for (int r = 0; r < 4; ++r) {
            float B1 = b1[m][r];
            int   I1 = (kb[m][r] >> 1) * 64 + rowbase + (kb[m][r] & 1) * 16 + (lane & 15);
            float B2 = b2[m][r];
            #pragma unroll
            for (int msk = 1; msk < 16; msk <<= 1) {
                float ob1 = __shfl_xor(B1, msk);
                int   oi1 = __shfl_xor(I1, msk);
                float ob2 = __shfl_xor(B2, msk);
                mrg(B1, I1, B2, ob1, oi1, ob2);
            }
            if ((lane & 15) == 0) {
                int sl = shalf + m * 16 + ((lane >> 4) << 2) + r;   // 0..127
                int ch = w >> 1;
                sb1[ch * 128 + sl] = B1;
                si1[ch * 128 + sl] = I1;
                sb2[ch * 128 + sl] = B2;
            }
        }
    }
    __syncthreads();
    if (tid < 128) {
        float B1 = sb1[tid]; int I1 = si1[tid]; float B2 = sb2[tid];
        mrg(B1, I1, B2, sb1[128 + tid], si1[128 + tid], sb2[128 + tid]);
        idx_out[n0 + tid] = I1;
        atomicAdd(&counts[I1], 1u);   // provisional count (rescore fixes deltas)
        if (B2 - B1 < MARGIN) {
            int p = atomicAdd(ambCnt, 1);
            ambList[p] = n0 + tid;
        }
    }
}

// ---- exact fp32 rescore: 16 samples/batch, 2 k-chunks in flight, prefetched E ----
__global__ __launch_bounds__(256) void k_rescore(const float* __restrict__ x,
                                                 const float* __restrict__ E,
                                                 const float* __restrict__ coln,
                                                 const int* __restrict__ ambCnt,
                                                 const int* __restrict__ ambList,
                                                 int* __restrict__ idx_out,
                                                 unsigned int* __restrict__ counts) {
    __shared__ float xs[RB][DD];
    __shared__ float xn[RB];
    __shared__ int   sid[RB];
    __shared__ float rb1[RB][256];
    __shared__ int   ri1[RB][256];

    const int tid = threadIdx.x;
    const int cnt = *ambCnt;
    const int nbatch = (cnt + RB - 1) / RB;

    for (int b = blockIdx.x; b < nbatch; b += gridDim.x) {
        const int e0 = b * RB;
        const int nb = min(RB, cnt - e0);
        __syncthreads();
        #pragma unroll
        for (int p = 0; p < 2; ++p) {
            int slot = p * 256 + tid;
            int e = slot >> 5, c = slot & 31;
            if (e < nb) {
                int s = ambList[e0 + e];
                if (c == 0) sid[e] = s;
                *(float4*)&xs[e][c * 4] = *(const float4*)&x[(size_t)s * DD + c * 4];
            } else {
                float4 z; z.x = z.y = z.z = z.w = 0.f;
                *(float4*)&xs[e][c * 4] = z;
            }
        }
        __syncthreads();
        if (tid < RB) {
            float a = 0.f;
            for (int d = 0; d < DD; ++d) a = fmaf(xs[tid][d], xs[tid][d], a);
            xn[tid] = a;
        }
        __syncthreads();

        float b1[RB]; int i1[RB];
        #pragma unroll
        for (int e = 0; e < RB; ++e) { b1[e] = 3.4e38f; i1[e] = 0; }

        for (int i = 0; i < 16; i += 2) {
            const int ka = i * 256 + tid;        // chunk A
            const int kb2 = ka + 256;            // chunk B (next i)
            const float* Ea = E + ka;
            const float* Eb = E + kb2;
            float acca[RB], accb[RB];
            #pragma unroll
            for (int e = 0; e < RB; ++e) { acca[e] = 0.f; accb[e] = 0.f; }

            // prefetch d4=0
            float4 eA, eB;
            eA.x = Ea[0];            eA.y = Ea[(size_t)1 * NR_EMB];
            eA.z = Ea[(size_t)2 * NR_EMB]; eA.w = Ea[(size_t)3 * NR_EMB];
            eB.x = Eb[0];            eB.y = Eb[(size_t)1 * NR_EMB];
            eB.z = Eb[(size_t)2 * NR_EMB]; eB.w = Eb[(size_t)3 * NR_EMB];

            for (int d4 = 0; d4 < 31; ++d4) {
                float4 nA, nB;
                const size_t dn = (size_t)(d4 * 4 + 4) * NR_EMB;
                nA.x = Ea[dn];                    nA.y = Ea[dn + NR_EMB];
                nA.z = Ea[dn + 2 * NR_EMB];       nA.w = Ea[dn + 3 * NR_EMB];
                nB.x = Eb[dn];                    nB.y = Eb[dn + NR_EMB];
                nB.z = Eb[dn + 2 * NR_EMB];       nB.w = Eb[dn + 3 * NR_EMB];
                #pragma unroll
                for (int e = 0; e < RB; ++e) {
                    float4 xv = *(const float4*)&xs[e][d4 * 4];
                    acca[e] = fmaf(xv.x, eA.x, acca[e]);
                    acca[e] = fmaf(xv.y, eA.y, acca[e]);
                    acca[e] = fmaf(xv.z, eA.z, acca[e]);
                    acca[e] = fmaf(xv.w, eA.w, acca[e]);
                    accb[e] = fmaf(xv.x, eB.x, accb[e]);
                    accb[e] = fmaf(xv.y, eB.y, accb[e]);
                    accb[e] = fmaf(xv.z, eB.z, accb[e]);
                    accb[e] = fmaf(xv.w, eB.w, accb[e]);
                }
                eA = nA; eB = nB;
            }
            #pragma unroll
            for (int e = 0; e < RB; ++e) {   // tail d4=31
                float4 xv = *(const float4*)&xs[e][124];
                acca[e] = fmaf(xv.x, eA.x, acca[e]);
                acca[e] = fmaf(xv.y, eA.y, acca[e]);
                acca[e] = fmaf(xv.z, eA.z, acca[e]);
                acca[e] = fmaf(xv.w, eA.w, acca[e]);
                accb[e] = fmaf(xv.x, eB.x, accb[e]);
                accb[e] = fmaf(xv.y, eB.y, accb[e]);
                accb[e] = fmaf(xv.z, eB.z, accb[e]);
                accb[e] = fmaf(xv.w, eB.w, accb[e]);
            }

            const float cna = coln[ka];
            const float cnb = coln[kb2];
            #pragma unroll
            for (int e = 0; e < RB; ++e) {
                float da = (xn[e] - 2.0f * acca[e]) + cna;   // numpy association order
                bool lta = da < b1[e];                       // ka ascending within thread
                i1[e] = lta ? ka : i1[e];
                b1[e] = lta ? da : b1[e];
                float db = (xn[e] - 2.0f * accb[e]) + cnb;
                bool ltb = db < b1[e];
                i1[e] = ltb ? kb2 : i1[e];
                b1[e] = ltb ? db : b1[e];
            }
        }

        #pragma unroll
        for (int e = 0; e < RB; ++e) { rb1[e][tid] = b1[e]; ri1[e][tid] = i1[e]; }
        __syncthreads();
        {
            int g = tid >> 4, l = tid & 15;   // 16 groups x 16 lanes
            float B = rb1[g][l]; int I = ri1[g][l];
            #pragma unroll
            for (int j = 1; j < 16; ++j) {
                float ob = rb1[g][l + 16 * j]; int oi = ri1[g][l + 16 * j];
                if (ob < B || (ob == B && oi < I)) { B = ob; I = oi; }
            }
            #pragma unroll
            for (int m = 1; m < 16; m <<= 1) {
                float ob = __shfl_xor(B, m, 16);
                int   oi = __shfl_xor(I, m, 16);
                if (ob < B || (ob == B && oi < I)) { B = ob; I = oi; }
            }
            if (l == 0 && g < nb) {
                int s = sid[g];
                int old = idx_out[s];
                if (I != old) {
                    atomicSub(&counts[old], 1u);
                    atomicAdd(&counts[I], 1u);
                    idx_out[s] = I;
                }
            }
        }
    }
}

// ---- fused stats + exclusive prefix (offsets + cursors) ----
__global__ __launch_bounds__(256) void k_statsprefix(const float* __restrict__ emaC,
                                                     const unsigned int* __restrict__ counts,
                                                     float* __restrict__ outC,
                                                     float* __restrict__ scal,
                                                     float* __restrict__ outPerp,
                                                     int* __restrict__ off,
                                                     int* __restrict__ cursor) {
    __shared__ float rs[256], rp[256];
    __shared__ int rc[256];
    const int tid = threadIdx.x;
    float sc = 0.f, sp = 0.f;
    int csum = 0;
    int lc[16];
    #pragma unroll
    for (int j = 0; j < 16; ++j) {
        int k = tid * 16 + j;
        int c = (int)counts[k];
        lc[j] = csum; csum += c;
        float nc = emaC[k] * 0.99f + (float)c * 0.01f;
        outC[k] = nc;
        sc += nc;
        float p = (float)c * (1.0f / 65536.0f);
        sp += p * logf(p + 1e-10f);
    }
    rs[tid] = sc; rp[tid] = sp; rc[tid] = csum;
    __syncthreads();
    for (int o = 1; o < 256; o <<= 1) {   // inclusive scan of rc
        int v = (tid >= o) ? rc[tid - o] : 0;
        __syncthreads();
        rc[tid] += v;
        __syncthreads();
    }
    const int base = rc[tid] - csum;
    #pragma unroll
    for (int j = 0; j < 16; ++j) {
        int k = tid * 16 + j;
        int o = base + lc[j];
        off[k] = o;
        cursor[k] = o;
    }
    for (int o = 128; o > 0; o >>= 1) {
        if (tid < o) { rs[tid] += rs[tid + o]; rp[tid] += rp[tid + o]; }
        __syncthreads();
    }
    if (tid == 0) {
        scal[0] = rs[0];
        outPerp[0] = expf(-rp[0]);
    }
}

// ---- CSR build: fill buckets ----
__global__ __launch_bounds__(256) void k_fill(const int* __restrict__ idx,
                                              int* __restrict__ cursor,
                                              int* __restrict__ bucket) {
    for (int i = blockIdx.x * 256 + threadIdx.x; i < NTOT; i += gridDim.x * 256) {
        int k = idx[i];
        int p = atomicAdd(&cursor[k], 1);
        bucket[p] = i;
    }
}

// ---- per-code dw sum (atomic-free, coalesced) ----
__global__ __launch_bounds__(128) void k_dw(const float* __restrict__ x,
                                            const int* __restrict__ off,
                                            const unsigned int* __restrict__ counts,
                                            const int* __restrict__ bucket,
                                            float* __restrict__ dwT) {
    const int k = blockIdx.x;
    const int d = threadIdx.x;
    const int o = off[k];
    const int c = (int)counts[k];
    float acc = 0.f;
    for (int p = 0; p < c; ++p) {
        int s = bucket[o + p];
        acc += x[(size_t)s * DD + d];
    }
    dwT[(size_t)k * DD + d] = acc;
}

__global__ __launch_bounds__(256) void k_emb(const float* __restrict__ emaDw,
                                             const float* __restrict__ emaC,
                                             const unsigned int* __restrict__ counts,
                                             const float* __restrict__ dwT,
                                             const float* __restrict__ scal,
                                             float* __restrict__ outDw,
                                             float* __restrict__ outEmb,
                                             float* __restrict__ embT) {
    int g = blockIdx.x * 256 + threadIdx.x;
    int d = g >> 12;
    int k = g & 4095;
    float dw  = emaDw[g] * 0.99f + dwT[k * DD + d] * 0.01f;
    float cnt = (float)counts[k];
    float nc  = emaC[k] * 0.99f + cnt * 0.01f;
    float n   = scal[0];
    float denom = n * (nc + 1e-5f) / (n + 0.04096f);
    float e = dw / denom;
    outDw[g]  = dw;
    outEmb[g] = e;
    embT[k * DD + d] = e;
}

// ---- gather + straight-through + loss partials: 8 floats/thread ----
__global__ __launch_bounds__(256) void k_gather(const float* __restrict__ x,
                                                const float* __restrict__ embT,
                                                const int* __restrict__ idx,
                                                float* __restrict__ q,
                                                float* __restrict__ lpart) {
    __shared__ float wred[4];
    int g = blockIdx.x * 256 + threadIdx.x;   // 0..1048575
    int n = g >> 4;          // sample
    int c = g & 15;          // 8-float chunk within row
    int k = idx[n];
    const float* ep = &embT[(size_t)k * DD + c * 8];
    const float* xp = &x[(size_t)n * DD + c * 8];
    float4 e0 = *(const float4*)(ep);
    float4 e1 = *(const float4*)(ep + 4);
    float4 x0 = *(const float4*)(xp);
    float4 x1 = *(const float4*)(xp + 4);
    float s = 0.f;
    float4 q0, q1;
    {
        float dx = e0.x - x0.x, dy = e0.y - x0.y, dz = e0.z - x0.z, dw = e0.w - x0.w;
        q0.x = x0.x + dx; q0.y = x0.y + dy; q0.z = x0.z + dz; q0.w = x0.w + dw;
        s += dx * dx + dy * dy + dz * dz + dw * dw;
    }
    {
        float dx = e1.x - x1.x, dy = e1.y - x1.y, dz = e1.z - x1.z, dw = e1.w - x1.w;
        q1.x = x1.x + dx; q1.y = x1.y + dy; q1.z = x1.z + dz; q1.w = x1.w + dw;
        s += dx * dx + dy * dy + dz * dz + dw * dw;
    }
    float* qp = &q[(size_t)n * DD + c * 8];
    *(float4*)(qp)     = q0;
    *(float4*)(qp + 4) = q1;
    #pragma unroll
    for (int off = 32; off > 0; off >>= 1) s += __shfl_down(s, off);
    if ((threadIdx.x & 63) == 0) wred[threadIdx.x >> 6] = s;
    __syncthreads();
    if (threadIdx.x == 0)
        lpart[blockIdx.x] = wred[0] + wred[1] + wred[2] + wred[3];
}

__global__ __launch_bounds__(256) void k_final(const float* __restrict__ lpart,
                                               float* __restrict__ outLoss) {
    __shared__ float r[256];
    float s = 0.f;
    for (int i = threadIdx.x; i < 4096; i += 256) s += lpart[i];
    r[threadIdx.x] = s;
    __syncthreads();
    for (int off = 128; off > 0; off >>= 1) {
        if (threadIdx.x < off) r[threadIdx.x] += r[threadIdx.x + off];
        __syncthreads();
    }
    if (threadIdx.x == 0) outLoss[0] = r[0] * (1.0f / 8388608.0f);
}

extern "C" void kernel_launch(void* const* d_in, const int* in_sizes, int n_in,
                              void* d_out, int out_size, void* d_ws, size_t ws_size,
                              hipStream_t stream) {
    const float* x     = (const float*)d_in[0];
    const float* E     = (const float*)d_in[1];
    const float* emaC  = (const float*)d_in[2];
    const float* emaDw = (const float*)d_in[3];
    float* out = (float*)d_out;
    char*  ws  = (char*)d_ws;

    unsigned int*   cnts  = (unsigned int*)(ws + WS_CNT);
    float*          scal  = (float*)(ws + WS_SCAL);
    int*            ambC  = (int*)(ws + WS_AMBC);
    float*          coln  = (float*)(ws + WS_COLN);
    int*            idx   = (int*)(ws + WS_IDX);
    float*          embT  = (float*)(ws + WS_EMBT);
    float*          lpart = (float*)(ws + WS_LPART);
    unsigned short* EtHb  = (unsigned short*)(ws + WS_ETH);
    unsigned short* EtLb  = (unsigned short*)(ws + WS_ETL);
    int*            ambL  = (int*)(ws + WS_AMBL);
    int*            off   = (int*)(ws + WS_OFF);
    int*            cur   = (int*)(ws + WS_CUR);
    int*            bkt   = (int*)(ws + WS_BKT);
    float*          dwT   = (float*)(ws + WS_DWT);

    hipMemsetAsync(ws, 0, WS_AMBC + 64u, stream);

    k_prep_e<<<64, 256, 0, stream>>>(E, EtHb, EtLb, coln);
    k_dist<<<NTOT / 128, 256, 0, stream>>>(x, EtHb, EtLb, coln, idx, cnts, ambC, ambL);
    k_rescore<<<1024, 256, 0, stream>>>(x, E, coln, ambC, ambL, idx, cnts);
    k_statsprefix<<<1, 256, 0, stream>>>(emaC, cnts, out + OUT_CLUS, scal, out + OUT_PERP,
                                         off, cur);
    k_fill<<<64, 256, 0, stream>>>(idx, cur, bkt);
    k_dw<<<NR_EMB, 128, 0, stream>>>(x, off, cnts, bkt, dwT);
    k_emb<<<(DD * NR_EMB) / 256, 256, 0, stream>>>(emaDw, emaC, cnts, dwT, scal,
                                                   out + OUT_DW, out + OUT_EMB, embT);
    k_gather<<<(NTOT * DD / 8) / 256, 256, 0, stream>>>(x, embT, idx, out + OUT_Q, lpart);
    k_final<<<1, 256, 0, stream>>>(lpart, out + OUT_LOSS);
}